// Round 2
// baseline (4030.570 us; speedup 1.0000x reference)
//
#include <hip/hip_runtime.h>
#include <hip/hip_cooperative_groups.h>

typedef unsigned short u16;
typedef unsigned int u32;
typedef __attribute__((ext_vector_type(8))) short bf16x8;
typedef __attribute__((ext_vector_type(4))) float f32x4;
typedef __attribute__((ext_vector_type(8))) u16 u16x8;

__device__ __forceinline__ u16 f2b(float f) {
  u32 u = __builtin_bit_cast(u32, f);
  u += 0x7fffu + ((u >> 16) & 1u);
  return (u16)(u >> 16);
}
__device__ __forceinline__ float b2f(u16 h) {
  u32 u = ((u32)h) << 16;
  return __builtin_bit_cast(float, u);
}
__device__ __forceinline__ f32x4 mfma16(bf16x8 a, bf16x8 b, f32x4 c) {
  return __builtin_amdgcn_mfma_f32_16x16x32_bf16(a, b, c, 0, 0, 0);
}

// ---------- cast W f32 [4][1024][1024] -> bf16 copy + per-layer transposed copy
__global__ __launch_bounds__(256) void cast_w_kernel(const float* __restrict__ W,
                                                     u16* __restrict__ Wb,
                                                     u16* __restrict__ WbT) {
  __shared__ u16 tile[64][65];
  int L = blockIdx.z, R0 = blockIdx.y * 64, C0 = blockIdx.x * 64;
  const float* Wl = W + (size_t)L * (1024 * 1024);
  u16* Wbl = Wb + (size_t)L * (1024 * 1024);
  u16* WbTl = WbT + (size_t)L * (1024 * 1024);
  int tr = threadIdx.x >> 6, tc = threadIdx.x & 63;
  for (int i = 0; i < 16; ++i) {
    int r = tr * 16 + i;
    u16 v = f2b(Wl[(size_t)(R0 + r) * 1024 + C0 + tc]);
    Wbl[(size_t)(R0 + r) * 1024 + C0 + tc] = v;
    tile[r][tc] = v;
  }
  __syncthreads();
  for (int i = 0; i < 16; ++i) {
    int r = tr * 16 + i;
    WbTl[(size_t)(C0 + r) * 1024 + R0 + tc] = tile[tc][r];
  }
}

// ---------- generic f32 -> bf16 cast (n multiple of 8)
__global__ __launch_bounds__(256) void cast_f32_bf16_kernel(const float* __restrict__ in,
                                                            u16* __restrict__ out, long n8) {
  long i = (long)blockIdx.x * 256 + threadIdx.x;
  long stride = (long)gridDim.x * 256;
  for (; i < n8; i += stride) {
    const float* s = in + i * 8;
    u16x8 o;
#pragma unroll
    for (int j = 0; j < 8; ++j) o[j] = f2b(s[j]);
    *(u16x8*)(out + i * 8) = o;
  }
}

// ---------- embedding gather -> e_bf [4096(=t*4+b)][512]
__global__ __launch_bounds__(256) void gather_e_kernel(const int* __restrict__ ids,
                                                       const float* __restrict__ embed,
                                                       u16* __restrict__ ebf) {
  int row = blockIdx.x * 4 + (threadIdx.x >> 6);
  int lane = threadIdx.x & 63;
  int t = row >> 2, b = row & 3;
  int id = ids[b * 1024 + t];
  const float* src = embed + (size_t)id * 512 + lane * 8;
  u16x8 o;
#pragma unroll
  for (int j = 0; j < 8; ++j) o[j] = f2b(src[j]);
  *(u16x8*)(ebf + (size_t)row * 512 + lane * 8) = o;
}

// ---------- Sall slot 0 = S_{-1} = concat(starter) broadcast over batch
__global__ __launch_bounds__(256) void init_s0_kernel(const float* __restrict__ starter,
                                                      u16* __restrict__ Sall) {
  int i = blockIdx.x * 256 + threadIdx.x;
  if (i < 2048) {
    u16 v = f2b(starter[i]);
    for (int b = 0; b < 4; ++b) Sall[(size_t)b * 2048 + i] = v;
  }
}

// ---------- copy D_i blocks into M/MT diagonals, B3 -> R block3, C0 -> U block0
__global__ __launch_bounds__(256) void assemble_kernel(const u16* __restrict__ Wb,
                                                       const u16* __restrict__ WbT,
                                                       u16* __restrict__ M, u16* __restrict__ MT,
                                                       u16* __restrict__ Rm, u16* __restrict__ Um) {
  int task = blockIdx.y;
  int e = blockIdx.x * 256 + threadIdx.x;  // 0..262143
  int r = e >> 9, c = e & 511;
  if (task < 4) {
    int i = task;
    u16 v = Wb[(size_t)i * 1048576 + (size_t)(512 + r) * 1024 + 512 + c];
    u16 vt = WbT[(size_t)i * 1048576 + (size_t)(512 + r) * 1024 + 512 + c];
    M[(size_t)(i * 512 + r) * 2048 + i * 512 + c] = v;
    MT[(size_t)(i * 512 + r) * 2048 + i * 512 + c] = vt;
  } else if (task == 4) {
    Rm[(size_t)r * 2048 + 3 * 512 + c] = Wb[(size_t)3 * 1048576 + (size_t)r * 1024 + 512 + c];
  } else {
    Um[(size_t)r * 512 + c] = Wb[(size_t)(512 + r) * 1024 + c];
  }
}

// ---------- bias chain: hnew = A_l h + bx_l ; k_l = C_l h + bs_l   (f32, tiny)
__global__ __launch_bounds__(256) void bias_step_kernel(const float* __restrict__ W,
                                                        const float* __restrict__ bv, int layer,
                                                        const float* __restrict__ hin,
                                                        float* __restrict__ hout,
                                                        float* __restrict__ kvec) {
  int wid = threadIdx.x >> 6, lane = threadIdx.x & 63;
  int gw = blockIdx.x * 4 + wid;
  for (int o = gw; o < 1024; o += 64) {
    const float* row = W + (size_t)layer * 1048576 + (size_t)o * 1024;
    float s = 0.f;
    for (int k = lane; k < 512; k += 64) s += row[k] * hin[k];
    for (int off = 32; off; off >>= 1) s += __shfl_down(s, off);
    if (lane == 0) {
      float v = s + bv[layer * 1024 + o];
      if (o < 512) hout[o] = v;
      else kvec[layer * 512 + (o - 512)] = v;
    }
  }
}

// ---------- batched 512x512x512 composer: Out[r,n] = sum_k A[r,k]*B[n,k], optional transposed copy
struct G512 { const u16* A; const u16* B; u16* C; u16* CT; int lda, ldb, ldc, ldt; };
struct G512Args { G512 g[8]; };

__global__ __launch_bounds__(256) void gemm512_kernel(G512Args args) {
  G512 d = args.g[blockIdx.z];
  int wid = threadIdx.x >> 6, lane = threadIdx.x & 63;
  int wr = wid >> 1, wc = wid & 1;
  int row0 = blockIdx.y * 64 + wr * 32, col0 = blockIdx.x * 64 + wc * 32;
  int fr = lane & 15, fk = (lane >> 4) * 8;
  f32x4 acc[2][2] = {};
  for (int kk = 0; kk < 512; kk += 32) {
    bf16x8 a[2], b[2];
#pragma unroll
    for (int m = 0; m < 2; ++m)
      a[m] = *(const bf16x8*)(d.A + (size_t)(row0 + m * 16 + fr) * d.lda + kk + fk);
#pragma unroll
    for (int n = 0; n < 2; ++n)
      b[n] = *(const bf16x8*)(d.B + (size_t)(col0 + n * 16 + fr) * d.ldb + kk + fk);
#pragma unroll
    for (int m = 0; m < 2; ++m)
#pragma unroll
      for (int n = 0; n < 2; ++n) acc[m][n] = mfma16(a[m], b[n], acc[m][n]);
  }
  int dr = (lane >> 4) * 4, dc = lane & 15;
  for (int m = 0; m < 2; ++m)
    for (int n = 0; n < 2; ++n)
#pragma unroll
      for (int j = 0; j < 4; ++j) {
        int r = row0 + m * 16 + dr + j, c = col0 + n * 16 + dc;
        u16 v = f2b(acc[m][n][j]);
        d.C[(size_t)r * d.ldc + c] = v;
        if (d.CT) d.CT[(size_t)c * d.ldt + r] = v;
      }
}

// ---------- triangular squaring: Mo = Mc*Mc over 10 nonzero 512x512 blocks, variable K.
// task t -> output block (i,j), K=(i-j+1)*512. Writes Mo and MoT (transposed copy).
__global__ __launch_bounds__(256) void sq_tri_kernel(const u16* __restrict__ Mc,
                                                     const u16* __restrict__ McT,
                                                     u16* __restrict__ Mo,
                                                     u16* __restrict__ MoT) {
  __shared__ u16 As[128 * 64];
  __shared__ u16 Bs[128 * 64];
  const int ti_[10] = {0, 1, 1, 2, 2, 2, 3, 3, 3, 3};
  const int tj_[10] = {0, 0, 1, 0, 1, 2, 0, 1, 2, 3};
  int t = blockIdx.z;
  int ib = ti_[t], jb = tj_[t];
  int K = (ib - jb + 1) << 9;
  const u16* A = Mc + (size_t)(ib * 512) * 2048 + jb * 512;
  const u16* B = McT + (size_t)(jb * 512) * 2048 + jb * 512;
  int tid = threadIdx.x;
  int wid = tid >> 6, lane = tid & 63;
  int wr = wid >> 1, wc = wid & 1;
  int fr = lane & 15, fkb = (lane >> 4) * 8;
  int rowt = blockIdx.y * 128, colt = blockIdx.x * 128;
  f32x4 acc[4][4] = {};
  for (int kk = 0; kk < K; kk += 64) {
#pragma unroll
    for (int i = 0; i < 4; ++i) {
      int q = i * 256 + tid;
      int r = q >> 3, kc = (q & 7) * 8;
      *(bf16x8*)&As[r * 64 + kc] = *(const bf16x8*)(A + (size_t)(rowt + r) * 2048 + kk + kc);
      *(bf16x8*)&Bs[r * 64 + kc] = *(const bf16x8*)(B + (size_t)(colt + r) * 2048 + kk + kc);
    }
    __syncthreads();
#pragma unroll
    for (int kh = 0; kh < 64; kh += 32) {
      bf16x8 a[4], b[4];
#pragma unroll
      for (int m = 0; m < 4; ++m) a[m] = *(const bf16x8*)&As[(wr * 64 + m * 16 + fr) * 64 + kh + fkb];
#pragma unroll
      for (int n = 0; n < 4; ++n) b[n] = *(const bf16x8*)&Bs[(wc * 64 + n * 16 + fr) * 64 + kh + fkb];
#pragma unroll
      for (int m = 0; m < 4; ++m)
#pragma unroll
        for (int n = 0; n < 4; ++n) acc[m][n] = mfma16(a[m], b[n], acc[m][n]);
    }
    __syncthreads();
  }
  int dr = (lane >> 4) * 4, dc = lane & 15;
  for (int m = 0; m < 4; ++m)
    for (int n = 0; n < 4; ++n)
#pragma unroll
      for (int j = 0; j < 4; ++j) {
        int r = rowt + wr * 64 + m * 16 + dr + j;
        int c = colt + wc * 64 + n * 16 + dc;
        u16 v = f2b(acc[m][n][j]);
        Mo[(size_t)(ib * 512 + r) * 2048 + jb * 512 + c] = v;
        MoT[(size_t)(jb * 512 + c) * 2048 + ib * 512 + r] = v;
      }
}

// ---------- main tiled GEMM: Out[r,n] = sum_k A[r,k]*B[n,k] (+bias[n]) (+prev[r,n])
// 128x128 tile, BK=64, LDS-staged. SWZ: XCD-contiguous (colt sweep inner over rows).
template <bool OUT_BF16, bool PERM, bool ADD_PREV, bool HAS_BIAS, bool SWZ>
__global__ __launch_bounds__(256) void gemm128_kernel(
    const u16* __restrict__ A, int lda, const u16* __restrict__ B, int ldb, int K,
    void* __restrict__ C, int ldc,
    const float* __restrict__ bias, const float* __restrict__ prev, int ldp) {
  __shared__ u16 As[128 * 64];
  __shared__ u16 Bs[128 * 64];
  int tid = threadIdx.x;
  int wid = tid >> 6, lane = tid & 63;
  int wr = wid >> 1, wc = wid & 1;
  int fr = lane & 15, fkb = (lane >> 4) * 8;
  int rowt, colt;
  if (SWZ) {  // 8000 blocks = 250 col-tiles x 32 row-tiles; each XCD gets 1000 contiguous lin
    int bid = blockIdx.x;
    int lin = (bid & 7) * 1000 + (bid >> 3);
    rowt = (lin & 31) * 128;
    colt = (lin >> 5) * 128;
  } else {
    rowt = blockIdx.y * 128;
    colt = blockIdx.x * 128;
  }
  f32x4 acc[4][4] = {};
  for (int kk = 0; kk < K; kk += 64) {
#pragma unroll
    for (int i = 0; i < 4; ++i) {
      int q = i * 256 + tid;
      int r = q >> 3, kc = (q & 7) * 8;
      *(bf16x8*)&As[r * 64 + kc] = *(const bf16x8*)(A + (size_t)(rowt + r) * lda + kk + kc);
      *(bf16x8*)&Bs[r * 64 + kc] = *(const bf16x8*)(B + (size_t)(colt + r) * ldb + kk + kc);
    }
    __syncthreads();
#pragma unroll
    for (int kh = 0; kh < 64; kh += 32) {
      bf16x8 a[4], b[4];
#pragma unroll
      for (int m = 0; m < 4; ++m) a[m] = *(const bf16x8*)&As[(wr * 64 + m * 16 + fr) * 64 + kh + fkb];
#pragma unroll
      for (int n = 0; n < 4; ++n) b[n] = *(const bf16x8*)&Bs[(wc * 64 + n * 16 + fr) * 64 + kh + fkb];
#pragma unroll
      for (int m = 0; m < 4; ++m)
#pragma unroll
        for (int n = 0; n < 4; ++n) acc[m][n] = mfma16(a[m], b[n], acc[m][n]);
    }
    __syncthreads();
  }
  int dr = (lane >> 4) * 4, dc = lane & 15;
  for (int m = 0; m < 4; ++m)
    for (int n = 0; n < 4; ++n) {
      int c = colt + wc * 64 + n * 16 + dc;
      float bvv = HAS_BIAS ? bias[c] : 0.f;
#pragma unroll
      for (int j = 0; j < 4; ++j) {
        int r = rowt + wr * 64 + m * 16 + dr + j;
        float v = acc[m][n][j] + bvv;
        if (ADD_PREV) v += prev[(size_t)r * ldp + c];
        int orow = PERM ? ((r & 3) * 1024 + (r >> 2)) : r;
        if (OUT_BF16) ((u16*)C)[(size_t)orow * ldc + c] = f2b(v);
        else ((float*)C)[(size_t)orow * ldc + c] = v;
      }
    }
}

// ---------- fused 3-pass scan (cooperative, grid 64 x 256).
// Block b: ct = b>>1 (64-col tile of 2048), rg = b&1 (64-row half of 128 rows).
// Triangular: col-tile in block-row i only needs K=(i+1)*512.
// Chunked row addressing: row r -> chunk c=r>>2, batch b=r&3, elem off = (r>>2)*cs + (r&3)*2048.
__device__ __forceinline__ void step128(const u16* __restrict__ Abase, int a_cs,
                                        const u16* __restrict__ M,
                                        const u16* __restrict__ Vbase, int v_cs,
                                        u16* __restrict__ Obase, int o_cs,
                                        int ct, int rg, int wv, int lane) {
  int i_blk = ct >> 3;
  int Keff = (i_blk + 1) << 9;
  int fr = lane & 15, fk = (lane >> 4) * 8;
  int r0 = rg * 64 + wv * 16;
  int ar = r0 + fr;
  const u16* Arow = Abase + (size_t)(ar >> 2) * a_cs + (size_t)(ar & 3) * 2048;
  const u16* Mbase = M + (size_t)(ct * 64 + fr) * 2048;
  f32x4 acc[4] = {};
  for (int k = 0; k < Keff; k += 32) {
    bf16x8 a = *(const bf16x8*)(Arow + k + fk);
#pragma unroll
    for (int n = 0; n < 4; ++n) {
      bf16x8 b = *(const bf16x8*)(Mbase + (size_t)n * 32768 + k + fk);
      acc[n] = mfma16(a, b, acc[n]);
    }
  }
  int dr = (lane >> 4) * 4, dc = lane & 15;
#pragma unroll
  for (int n = 0; n < 4; ++n) {
    int col = ct * 64 + n * 16 + dc;
#pragma unroll
    for (int j = 0; j < 4; ++j) {
      int rr = r0 + dr + j;
      size_t voff = (size_t)(rr >> 2) * v_cs + (size_t)(rr & 3) * 2048 + col;
      size_t ooff = (size_t)(rr >> 2) * o_cs + (size_t)(rr & 3) * 2048 + col;
      Obase[ooff] = f2b(acc[n][j] + b2f(Vbase[voff]));
    }
  }
}

// 4-row step (pass 2): O[4][2048] = A[4][2048] @ M32^T + V. Waves = col frags.
__device__ __forceinline__ void step4(const u16* __restrict__ A, const u16* __restrict__ M32,
                                      const u16* __restrict__ V, u16* __restrict__ O,
                                      int ct, int wv, int lane) {
  int i_blk = ct >> 3;
  int Keff = (i_blk + 1) << 9;
  int fr = lane & 15, fk = (lane >> 4) * 8;
  int ar = fr < 4 ? fr : 3;  // clamp; rows 4..15 discarded
  const u16* Arow = A + (size_t)ar * 2048;
  const u16* Mb = M32 + (size_t)(ct * 64 + wv * 16 + fr) * 2048;
  f32x4 acc = {};
  for (int k = 0; k < Keff; k += 32) {
    bf16x8 a = *(const bf16x8*)(Arow + k + fk);
    bf16x8 b = *(const bf16x8*)(Mb + k + fk);
    acc = mfma16(a, b, acc);
  }
  int dr = (lane >> 4) * 4, dc = lane & 15;
  int col = ct * 64 + wv * 16 + dc;
#pragma unroll
  for (int j = 0; j < 4; ++j) {
    int rr = dr + j;
    if (rr < 4) O[(size_t)rr * 2048 + col] = f2b(acc[j] + b2f(V[(size_t)rr * 2048 + col]));
  }
}

__global__ __launch_bounds__(256) void scan_coop_kernel(
    const u16* __restrict__ M, const u16* __restrict__ M32, const u16* __restrict__ vbuf,
    u16* __restrict__ Sall, u16* __restrict__ ping0, u16* __restrict__ ping1) {
  cooperative_groups::grid_group grid = cooperative_groups::this_grid();
  int blk = blockIdx.x;
  int ct = blk >> 1, rg = blk & 1;
  int wv = threadIdx.x >> 6, lane = threadIdx.x & 63;

  // pass 1: S_hat_j = M S_hat_{j-1} + v_j, S_hat_0 = v_0 (read in place from vbuf at j=1)
  const u16* A = vbuf;
  int a_cs = 262144;
  for (int j = 1; j <= 31; ++j) {
    u16* O = (j & 1) ? ping0 : ping1;
    step128(A, a_cs, M, vbuf + (size_t)j * 8192, 262144, O, 8192, ct, rg, wv, lane);
    grid.sync();
    A = O;
    a_cs = 8192;
  }
  // wstack = ping0 (j=31 odd)

  // pass 2: Sall[32(c+1)] = M32 * Sall[32c] + w_c
  for (int c = 0; c < 31; ++c) {
    if (rg == 0)
      step4(Sall + (size_t)c * 262144, M32, ping0 + (size_t)c * 8192,
            Sall + (size_t)(c + 1) * 262144, ct, wv, lane);
    grid.sync();
  }

  // pass 3: Sall[32c+j+1] = M * Sall[32c+j] + v_{c,j}
  for (int j = 0; j < 31; ++j) {
    step128(Sall + (size_t)j * 8192, 262144, M, vbuf + (size_t)j * 8192, 262144,
            Sall + (size_t)(j + 1) * 8192, 262144, ct, rg, wv, lane);
    grid.sync();
  }
}

static inline size_t alignup(size_t x) { return (x + 255) & ~(size_t)255; }

extern "C" void kernel_launch(void* const* d_in, const int* in_sizes, int n_in,
                              void* d_out, int out_size, void* d_ws, size_t ws_size,
                              hipStream_t stream) {
  const int* ids = (const int*)d_in[0];
  const float* embed = (const float*)d_in[1];
  const float* starter = (const float*)d_in[2];
  const float* W = (const float*)d_in[3];
  const float* bvec = (const float*)d_in[4];
  const float* Wout = (const float*)d_in[5];
  const float* bout = (const float*)d_in[6];
  float* out = (float*)d_out;

  char* p = (char*)d_ws;
  auto alloc = [&](size_t bytes) { char* q = p; p += alignup(bytes); return q; };
  u16* Wbf = (u16*)alloc(8388608);
  u16* WbT = (u16*)alloc(8388608);
  u16* Mm = (u16*)alloc(8388608);
  u16* MTm = (u16*)alloc(8388608);
  u16* SQ0 = (u16*)alloc(8388608);
  u16* SQ1 = (u16*)alloc(8388608);
  u16* SQ2 = (u16*)alloc(8388608);
  u16* SQ3 = (u16*)alloc(8388608);
  u16* X2 = (u16*)alloc(524288);  u16* X2T = (u16*)alloc(524288);
  u16* X3 = (u16*)alloc(524288);  u16* X3T = (u16*)alloc(524288);
  u16* P1 = (u16*)alloc(524288);  u16* P1T = (u16*)alloc(524288);
  u16* P2 = (u16*)alloc(524288);  u16* P2T = (u16*)alloc(524288);
  u16* P3 = (u16*)alloc(524288);  u16* P3T = (u16*)alloc(524288);
  u16* Um = (u16*)alloc(2097152);
  u16* Rm = (u16*)alloc(2097152);
  u16* Qm = (u16*)alloc(524288);
  u16* ebf = (u16*)alloc(4194304);
  u16* vbuf = (u16*)alloc(16777216);
  u16* Sall = (u16*)alloc(16777216);
  u16* ping0 = (u16*)alloc(524288);
  u16* ping1 = (u16*)alloc(524288);
  float* yacc = (float*)alloc(8388608);
  u16* ybf = (u16*)alloc(4194304);
  u16* WoutB = (u16*)alloc(32768000);
  float* kvec = (float*)alloc(8192);
  float* h0 = (float*)alloc(2048);
  float* h1 = (float*)alloc(2048);
  if ((size_t)(p - (char*)d_ws) > ws_size) return;

  // h0 = 0 for bias chain. (M/MT zero blocks are never read anywhere: scan/squarings
  // restrict K to the lower-triangular block range, so no memset of Mm/MTm needed.)
  hipMemsetAsync(h0, 0, 2048, stream);

  cast_w_kernel<<<dim3(16, 16, 4), 256, 0, stream>>>(W, Wbf, WbT);
  cast_f32_bf16_kernel<<<4096, 256, 0, stream>>>(Wout, WoutB, 32000L * 512 / 8);
  gather_e_kernel<<<1024, 256, 0, stream>>>(ids, embed, ebf);
  init_s0_kernel<<<8, 256, 0, stream>>>(starter, Sall);
  assemble_kernel<<<dim3(1024, 6), 256, 0, stream>>>(Wbf, WbT, Mm, MTm, Rm, Um);

  {  // bias chain
    const float* hin = h0;
    float* hout = h1;
    for (int l = 0; l < 4; ++l) {
      bias_step_kernel<<<16, 256, 0, stream>>>(W, bvec, l, hin, hout, kvec);
      float* t = (float*)hin; hin = hout; hout = t;
    }
  }
  const float* cvec = h0;  // h after layer 3

  auto wb = [&](int i) { return Wbf + (size_t)i * 1048576; };
  auto wbt = [&](int i) { return WbT + (size_t)i * 1048576; };
  const size_t Apos = 0, Cpos = (size_t)512 * 1024;
  auto mblk = [&](int i, int j) { return Mm + (size_t)(i * 512) * 2048 + j * 512; };
  auto mtblk = [&](int i, int j) { return MTm + (size_t)(j * 512) * 2048 + i * 512; };

  {  // level A
    G512Args a{};
    int n = 0;
    auto add = [&](const u16* A_, int lda, const u16* B_, int ldb, u16* C_, int ldc, u16* CT_, int ldt) {
      a.g[n++] = G512{A_, B_, C_, CT_, lda, ldb, ldc, ldt};
    };
    add(wb(1) + Apos, 1024, wbt(0) + Apos, 1024, X2, 512, X2T, 512);
    add(wb(1) + Apos, 1024, wbt(0) + Cpos, 1024, P1, 512, P1T, 512);
    add(wb(2) + Apos, 1024, wbt(1) + Cpos, 1024, P3, 512, P3T, 512);
    add(wb(1) + Cpos, 1024, wbt(0) + Cpos, 1024, mblk(1, 0), 2048, mtblk(1, 0), 2048);
    add(wb(2) + Cpos, 1024, wbt(1) + Cpos, 1024, mblk(2, 1), 2048, mtblk(2, 1), 2048);
    add(wb(3) + Apos, 1024, wbt(2) + Cpos, 1024, Rm + 2 * 512, 2048, nullptr, 0);
    add(wb(3) + Cpos, 1024, wbt(2) + Cpos, 1024, mblk(3, 2), 2048, mtblk(3, 2), 2048);
    add(wb(1) + Cpos, 1024, wbt(0) + Apos, 1024, Um + (size_t)1 * 262144, 512, nullptr, 0);
    gemm512_kernel<<<dim3(8, 8, 8), 256, 0, stream>>>(a);
  }
  {  // level B
    G512Args a{};
    int n = 0;
    auto add = [&](const u16* A_, int lda, const u16* B_, int ldb, u16* C_, int ldc, u16* CT_, int ldt) {
      a.g[n++] = G512{A_, B_, C_, CT_, lda, ldb, ldc, ldt};
    };
    add(wb(2) + Apos, 1024, X2T, 512, X3, 512, X3T, 512);
    add(wb(2) + Apos, 1024, P1T, 512, P2, 512, P2T, 512);
    add(wb(2) + Cpos, 1024, P1T, 512, mblk(2, 0), 2048, mtblk(2, 0), 2048);
    add(wb(3) + Apos, 1024, P3T, 512, Rm + 512, 2048, nullptr, 0);
    add(wb(3) + Cpos, 1024, P3T, 512, mblk(3, 1), 2048, mtblk(3, 1), 2048);
    add(wb(2) + Cpos, 1024, X2T, 512, Um + (size_t)2 * 262144, 512, nullptr, 0);
    gemm512_kernel<<<dim3(8, 8, 6), 256, 0, stream>>>(a);
  }
  {  // level C
    G512Args a{};
    int n = 0;
    auto add = [&](const u16* A_, int lda, const u16* B_, int ldb, u16* C_, int ldc, u16* CT_, int ldt) {
      a.g[n++] = G512{A_, B_, C_, CT_, lda, ldb, ldc, ldt};
    };
    add(wb(3) + Apos, 1024, X3T, 512, Qm, 512, nullptr, 0);
    add(wb(3) + Apos, 1024, P2T, 512, Rm, 2048, nullptr, 0);
    add(wb(3) + Cpos, 1024, P2T, 512, mblk(3, 0), 2048, mtblk(3, 0), 2048);
    add(wb(3) + Cpos, 1024, X3T, 512, Um + (size_t)3 * 262144, 512, nullptr, 0);
    gemm512_kernel<<<dim3(8, 8, 4), 256, 0, stream>>>(a);
  }

  // M^32 via 5 triangular squarings (each writes value + transposed copy)
  u16* cur = Mm;
  u16* curT = MTm;
  for (int s = 0; s < 5; ++s) {
    u16* nx = (s & 1) ? SQ2 : SQ0;
    u16* nxT = (s & 1) ? SQ3 : SQ1;
    sq_tri_kernel<<<dim3(4, 4, 10), 256, 0, stream>>>(cur, curT, nx, nxT);
    cur = nx; curT = nxT;
  }
  u16* M32 = cur;  // SQ0

  // v = e @ U^T + k   [4096, 2048] bf16
  gemm128_kernel<true, false, false, true, false><<<dim3(16, 32), 256, 0, stream>>>(
      ebf, 512, Um, 512, 512, (void*)vbuf, 2048, kvec, nullptr, 0);

  // fused 3-pass scan (93 grid syncs)
  {
    void* args[] = {(void*)&Mm, (void*)&M32, (void*)&vbuf, (void*)&Sall,
                    (void*)&ping0, (void*)&ping1};
    hipLaunchCooperativeKernel((void*)scan_coop_kernel, dim3(64), dim3(256), args, 0, stream);
  }

  // y = Sall @ R^T + e @ Q^T + c
  gemm128_kernel<false, false, false, false, false><<<dim3(4, 32), 256, 0, stream>>>(
      Sall, 2048, Rm, 2048, 2048, (void*)yacc, 512, nullptr, nullptr, 0);
  gemm128_kernel<true, false, true, true, false><<<dim3(4, 32), 256, 0, stream>>>(
      ebf, 512, Qm, 512, 512, (void*)ybf, 512, cvec, yacc, 512);

  // logits = y @ Wout^T + bout, rows permuted (t*4+b) -> (b*1024+t); XCD-swizzled grid
  gemm128_kernel<false, true, false, true, true><<<dim3(8000), 256, 0, stream>>>(
      ybf, 512, WoutB, 512, 512, (void*)out, 32000, bout, nullptr, 0);
}

// Round 3
// 2971.974 us; speedup vs baseline: 1.3562x; 1.3562x over previous
//
#include <hip/hip_runtime.h>
#include <hip/hip_cooperative_groups.h>

typedef unsigned short u16;
typedef unsigned int u32;
typedef __attribute__((ext_vector_type(8))) short bf16x8;
typedef __attribute__((ext_vector_type(4))) float f32x4;
typedef __attribute__((ext_vector_type(8))) u16 u16x8;

__device__ __forceinline__ u16 f2b(float f) {
  u32 u = __builtin_bit_cast(u32, f);
  u += 0x7fffu + ((u >> 16) & 1u);
  return (u16)(u >> 16);
}
__device__ __forceinline__ float b2f(u16 h) {
  u32 u = ((u32)h) << 16;
  return __builtin_bit_cast(float, u);
}
__device__ __forceinline__ f32x4 mfma16(bf16x8 a, bf16x8 b, f32x4 c) {
  return __builtin_amdgcn_mfma_f32_16x16x32_bf16(a, b, c, 0, 0, 0);
}

// ---------- cast W f32 [4][1024][1024] -> bf16 copy + per-layer transposed copy
__global__ __launch_bounds__(256) void cast_w_kernel(const float* __restrict__ W,
                                                     u16* __restrict__ Wb,
                                                     u16* __restrict__ WbT) {
  __shared__ u16 tile[64][65];
  int L = blockIdx.z, R0 = blockIdx.y * 64, C0 = blockIdx.x * 64;
  const float* Wl = W + (size_t)L * (1024 * 1024);
  u16* Wbl = Wb + (size_t)L * (1024 * 1024);
  u16* WbTl = WbT + (size_t)L * (1024 * 1024);
  int tr = threadIdx.x >> 6, tc = threadIdx.x & 63;
  for (int i = 0; i < 16; ++i) {
    int r = tr * 16 + i;
    u16 v = f2b(Wl[(size_t)(R0 + r) * 1024 + C0 + tc]);
    Wbl[(size_t)(R0 + r) * 1024 + C0 + tc] = v;
    tile[r][tc] = v;
  }
  __syncthreads();
  for (int i = 0; i < 16; ++i) {
    int r = tr * 16 + i;
    WbTl[(size_t)(C0 + r) * 1024 + R0 + tc] = tile[tc][r];
  }
}

// ---------- generic f32 -> bf16 cast (n multiple of 8)
__global__ __launch_bounds__(256) void cast_f32_bf16_kernel(const float* __restrict__ in,
                                                            u16* __restrict__ out, long n8) {
  long i = (long)blockIdx.x * 256 + threadIdx.x;
  long stride = (long)gridDim.x * 256;
  for (; i < n8; i += stride) {
    const float* s = in + i * 8;
    u16x8 o;
#pragma unroll
    for (int j = 0; j < 8; ++j) o[j] = f2b(s[j]);
    *(u16x8*)(out + i * 8) = o;
  }
}

// ---------- embedding gather -> e_bf [4096(=t*4+b)][512]
__global__ __launch_bounds__(256) void gather_e_kernel(const int* __restrict__ ids,
                                                       const float* __restrict__ embed,
                                                       u16* __restrict__ ebf) {
  int row = blockIdx.x * 4 + (threadIdx.x >> 6);
  int lane = threadIdx.x & 63;
  int t = row >> 2, b = row & 3;
  int id = ids[b * 1024 + t];
  const float* src = embed + (size_t)id * 512 + lane * 8;
  u16x8 o;
#pragma unroll
  for (int j = 0; j < 8; ++j) o[j] = f2b(src[j]);
  *(u16x8*)(ebf + (size_t)row * 512 + lane * 8) = o;
}

// ---------- Sall slot 0 = S_{-1} = concat(starter) broadcast over batch
__global__ __launch_bounds__(256) void init_s0_kernel(const float* __restrict__ starter,
                                                      u16* __restrict__ Sall) {
  int i = blockIdx.x * 256 + threadIdx.x;
  if (i < 2048) {
    u16 v = f2b(starter[i]);
    for (int b = 0; b < 4; ++b) Sall[(size_t)b * 2048 + i] = v;
  }
}

// ---------- copy D_i blocks into M/MT diagonals, B3 -> R block3, C0 -> U block0
__global__ __launch_bounds__(256) void assemble_kernel(const u16* __restrict__ Wb,
                                                       const u16* __restrict__ WbT,
                                                       u16* __restrict__ M, u16* __restrict__ MT,
                                                       u16* __restrict__ Rm, u16* __restrict__ Um) {
  int task = blockIdx.y;
  int e = blockIdx.x * 256 + threadIdx.x;  // 0..262143
  int r = e >> 9, c = e & 511;
  if (task < 4) {
    int i = task;
    u16 v = Wb[(size_t)i * 1048576 + (size_t)(512 + r) * 1024 + 512 + c];
    u16 vt = WbT[(size_t)i * 1048576 + (size_t)(512 + r) * 1024 + 512 + c];
    M[(size_t)(i * 512 + r) * 2048 + i * 512 + c] = v;
    MT[(size_t)(i * 512 + r) * 2048 + i * 512 + c] = vt;
  } else if (task == 4) {
    Rm[(size_t)r * 2048 + 3 * 512 + c] = Wb[(size_t)3 * 1048576 + (size_t)r * 1024 + 512 + c];
  } else {
    Um[(size_t)r * 512 + c] = Wb[(size_t)(512 + r) * 1024 + c];
  }
}

// ---------- bias chain: hnew = A_l h + bx_l ; k_l = C_l h + bs_l   (f32, tiny)
__global__ __launch_bounds__(256) void bias_step_kernel(const float* __restrict__ W,
                                                        const float* __restrict__ bv, int layer,
                                                        const float* __restrict__ hin,
                                                        float* __restrict__ hout,
                                                        float* __restrict__ kvec) {
  int wid = threadIdx.x >> 6, lane = threadIdx.x & 63;
  int gw = blockIdx.x * 4 + wid;
  for (int o = gw; o < 1024; o += 64) {
    const float* row = W + (size_t)layer * 1048576 + (size_t)o * 1024;
    float s = 0.f;
    for (int k = lane; k < 512; k += 64) s += row[k] * hin[k];
    for (int off = 32; off; off >>= 1) s += __shfl_down(s, off);
    if (lane == 0) {
      float v = s + bv[layer * 1024 + o];
      if (o < 512) hout[o] = v;
      else kvec[layer * 512 + (o - 512)] = v;
    }
  }
}

// ---------- batched 512x512x512 composer: Out[r,n] = sum_k A[r,k]*B[n,k], optional transposed copy
struct G512 { const u16* A; const u16* B; u16* C; u16* CT; int lda, ldb, ldc, ldt; };
struct G512Args { G512 g[8]; };

__global__ __launch_bounds__(256) void gemm512_kernel(G512Args args) {
  G512 d = args.g[blockIdx.z];
  int wid = threadIdx.x >> 6, lane = threadIdx.x & 63;
  int wr = wid >> 1, wc = wid & 1;
  int row0 = blockIdx.y * 64 + wr * 32, col0 = blockIdx.x * 64 + wc * 32;
  int fr = lane & 15, fk = (lane >> 4) * 8;
  f32x4 acc[2][2] = {};
  for (int kk = 0; kk < 512; kk += 32) {
    bf16x8 a[2], b[2];
#pragma unroll
    for (int m = 0; m < 2; ++m)
      a[m] = *(const bf16x8*)(d.A + (size_t)(row0 + m * 16 + fr) * d.lda + kk + fk);
#pragma unroll
    for (int n = 0; n < 2; ++n)
      b[n] = *(const bf16x8*)(d.B + (size_t)(col0 + n * 16 + fr) * d.ldb + kk + fk);
#pragma unroll
    for (int m = 0; m < 2; ++m)
#pragma unroll
      for (int n = 0; n < 2; ++n) acc[m][n] = mfma16(a[m], b[n], acc[m][n]);
  }
  int dr = (lane >> 4) * 4, dc = lane & 15;
  for (int m = 0; m < 2; ++m)
    for (int n = 0; n < 2; ++n)
#pragma unroll
      for (int j = 0; j < 4; ++j) {
        int r = row0 + m * 16 + dr + j, c = col0 + n * 16 + dc;
        u16 v = f2b(acc[m][n][j]);
        d.C[(size_t)r * d.ldc + c] = v;
        if (d.CT) d.CT[(size_t)c * d.ldt + r] = v;
      }
}

// ---------- triangular squaring: Mo = Mc*Mc over 10 nonzero 512x512 blocks, variable K.
__global__ __launch_bounds__(256) void sq_tri_kernel(const u16* __restrict__ Mc,
                                                     const u16* __restrict__ McT,
                                                     u16* __restrict__ Mo,
                                                     u16* __restrict__ MoT) {
  __shared__ u16 As[128 * 64];
  __shared__ u16 Bs[128 * 64];
  const int ti_[10] = {0, 1, 1, 2, 2, 2, 3, 3, 3, 3};
  const int tj_[10] = {0, 0, 1, 0, 1, 2, 0, 1, 2, 3};
  int t = blockIdx.z;
  int ib = ti_[t], jb = tj_[t];
  int K = (ib - jb + 1) << 9;
  const u16* A = Mc + (size_t)(ib * 512) * 2048 + jb * 512;
  const u16* B = McT + (size_t)(jb * 512) * 2048 + jb * 512;
  int tid = threadIdx.x;
  int wid = tid >> 6, lane = tid & 63;
  int wr = wid >> 1, wc = wid & 1;
  int fr = lane & 15, fkb = (lane >> 4) * 8;
  int rowt = blockIdx.y * 128, colt = blockIdx.x * 128;
  f32x4 acc[4][4] = {};
  for (int kk = 0; kk < K; kk += 64) {
#pragma unroll
    for (int i = 0; i < 4; ++i) {
      int q = i * 256 + tid;
      int r = q >> 3, kc = (q & 7) * 8;
      *(bf16x8*)&As[r * 64 + kc] = *(const bf16x8*)(A + (size_t)(rowt + r) * 2048 + kk + kc);
      *(bf16x8*)&Bs[r * 64 + kc] = *(const bf16x8*)(B + (size_t)(colt + r) * 2048 + kk + kc);
    }
    __syncthreads();
#pragma unroll
    for (int kh = 0; kh < 64; kh += 32) {
      bf16x8 a[4], b[4];
#pragma unroll
      for (int m = 0; m < 4; ++m) a[m] = *(const bf16x8*)&As[(wr * 64 + m * 16 + fr) * 64 + kh + fkb];
#pragma unroll
      for (int n = 0; n < 4; ++n) b[n] = *(const bf16x8*)&Bs[(wc * 64 + n * 16 + fr) * 64 + kh + fkb];
#pragma unroll
      for (int m = 0; m < 4; ++m)
#pragma unroll
        for (int n = 0; n < 4; ++n) acc[m][n] = mfma16(a[m], b[n], acc[m][n]);
    }
    __syncthreads();
  }
  int dr = (lane >> 4) * 4, dc = lane & 15;
  for (int m = 0; m < 4; ++m)
    for (int n = 0; n < 4; ++n)
#pragma unroll
      for (int j = 0; j < 4; ++j) {
        int r = rowt + wr * 64 + m * 16 + dr + j;
        int c = colt + wc * 64 + n * 16 + dc;
        u16 v = f2b(acc[m][n][j]);
        Mo[(size_t)(ib * 512 + r) * 2048 + jb * 512 + c] = v;
        MoT[(size_t)(jb * 512 + c) * 2048 + ib * 512 + r] = v;
      }
}

// ---------- main tiled GEMM: Out[r,n] = sum_k A[r,k]*B[n,k] (+bias[n]) (+prev[r,n])
template <bool OUT_BF16, bool PERM, bool ADD_PREV, bool HAS_BIAS, bool SWZ>
__global__ __launch_bounds__(256) void gemm128_kernel(
    const u16* __restrict__ A, int lda, const u16* __restrict__ B, int ldb, int K,
    void* __restrict__ C, int ldc,
    const float* __restrict__ bias, const float* __restrict__ prev, int ldp) {
  __shared__ u16 As[128 * 64];
  __shared__ u16 Bs[128 * 64];
  int tid = threadIdx.x;
  int wid = tid >> 6, lane = tid & 63;
  int wr = wid >> 1, wc = wid & 1;
  int fr = lane & 15, fkb = (lane >> 4) * 8;
  int rowt, colt;
  if (SWZ) {
    int bid = blockIdx.x;
    int lin = (bid & 7) * 1000 + (bid >> 3);
    rowt = (lin & 31) * 128;
    colt = (lin >> 5) * 128;
  } else {
    rowt = blockIdx.y * 128;
    colt = blockIdx.x * 128;
  }
  f32x4 acc[4][4] = {};
  for (int kk = 0; kk < K; kk += 64) {
#pragma unroll
    for (int i = 0; i < 4; ++i) {
      int q = i * 256 + tid;
      int r = q >> 3, kc = (q & 7) * 8;
      *(bf16x8*)&As[r * 64 + kc] = *(const bf16x8*)(A + (size_t)(rowt + r) * lda + kk + kc);
      *(bf16x8*)&Bs[r * 64 + kc] = *(const bf16x8*)(B + (size_t)(colt + r) * ldb + kk + kc);
    }
    __syncthreads();
#pragma unroll
    for (int kh = 0; kh < 64; kh += 32) {
      bf16x8 a[4], b[4];
#pragma unroll
      for (int m = 0; m < 4; ++m) a[m] = *(const bf16x8*)&As[(wr * 64 + m * 16 + fr) * 64 + kh + fkb];
#pragma unroll
      for (int n = 0; n < 4; ++n) b[n] = *(const bf16x8*)&Bs[(wc * 64 + n * 16 + fr) * 64 + kh + fkb];
#pragma unroll
      for (int m = 0; m < 4; ++m)
#pragma unroll
        for (int n = 0; n < 4; ++n) acc[m][n] = mfma16(a[m], b[n], acc[m][n]);
    }
    __syncthreads();
  }
  int dr = (lane >> 4) * 4, dc = lane & 15;
  for (int m = 0; m < 4; ++m)
    for (int n = 0; n < 4; ++n) {
      int c = colt + wc * 64 + n * 16 + dc;
      float bvv = HAS_BIAS ? bias[c] : 0.f;
#pragma unroll
      for (int j = 0; j < 4; ++j) {
        int r = rowt + wr * 64 + m * 16 + dr + j;
        float v = acc[m][n][j] + bvv;
        if (ADD_PREV) v += prev[(size_t)r * ldp + c];
        int orow = PERM ? ((r & 3) * 1024 + (r >> 2)) : r;
        if (OUT_BF16) ((u16*)C)[(size_t)orow * ldc + c] = f2b(v);
        else ((float*)C)[(size_t)orow * ldc + c] = v;
      }
    }
}

// ======================================================================
// Fused 3-pass scan, LDS-resident M.
// 128 blocks x 512 threads. Block: ct = blk>>1 (32-col tile of 2048), rg = blk&1
// (64-row half of the 128 state rows). Triangular: block-row i = ct>>4 needs
// K = (i+1)*512 only. M slice [32 rows x Keff] staged in LDS, XOR-swizzled
// (byte ^= (row&7)<<4) for conflict-free ds_read_b128 fragments.
// LDS: [0,131072) M slice; [131072, +8704) f32 reduce buffer.
// ======================================================================

__device__ __forceinline__ void stage_slice(const u16* __restrict__ src, char* smem,
                                            int ct, int Keff, int rowb, int wid, int lane) {
  int cpr = Keff >> 3;  // 16B chunks per row
  for (int row = wid * 4; row < wid * 4 + 4; ++row) {
    const u16* srow = src + (size_t)(ct * 32 + row) * 2048;
    int rb = row * rowb, sw = (row & 7) << 4;
    for (int c0 = lane; c0 < cpr; c0 += 64) {
      uint4 v = *(const uint4*)(srow + c0 * 8);
      *(uint4*)(smem + ((rb + c0 * 16) ^ sw)) = v;
    }
  }
}

// one scan step on [128 rows x 32 cols]: O = A @ Mlds^T + V (chunked row layout:
// row r -> (r>>2)*cs + (r&3)*2048). Waves: rw=wid>>1 row-group (16 rows), ks=wid&1 K-half.
__device__ __forceinline__ void step128(const char* smem, float* red,
                                        const u16* __restrict__ Abase, int a_cs,
                                        const u16* __restrict__ Vbase, int v_cs,
                                        u16* __restrict__ Obase, int o_cs,
                                        int ct, int rg, int Keff, int rowb, int wid, int lane) {
  int ks = wid & 1, rw = wid >> 1;
  int fr = lane & 15, fk8 = (lane >> 4) * 8;
  int r0 = rg * 64 + rw * 16;
  int K2 = Keff >> 1, kw = ks * K2;
  int ar = r0 + fr;
  const u16* Arow = Abase + (size_t)(ar >> 2) * a_cs + (size_t)(ar & 3) * 2048 + kw + fk8;
  int off0 = fr * rowb + (kw + fk8) * 2;
  int off1 = off0 + 16 * rowb;
  int sw = (fr & 7) << 4;
  f32x4 acc0 = {}, acc1 = {};
  for (int kk = 0; kk < K2; kk += 32) {
    bf16x8 a = *(const bf16x8*)(Arow + kk);
    bf16x8 b0 = *(const bf16x8*)(smem + ((off0 + kk * 2) ^ sw));
    bf16x8 b1 = *(const bf16x8*)(smem + ((off1 + kk * 2) ^ sw));
    acc0 = mfma16(a, b0, acc0);
    acc1 = mfma16(a, b1, acc1);
  }
  int dr = (lane >> 4) * 4, dc = lane & 15;
  float* rp = red + rw * 528;
  if (ks == 1) {
#pragma unroll
    for (int j = 0; j < 4; ++j) {
      rp[(dr + j) * 33 + dc] = acc0[j];
      rp[(dr + j) * 33 + 16 + dc] = acc1[j];
    }
  }
  __syncthreads();
  if (ks == 0) {
#pragma unroll
    for (int j = 0; j < 4; ++j) {
      int rr = r0 + dr + j;
      size_t vb = (size_t)(rr >> 2) * v_cs + (size_t)(rr & 3) * 2048 + ct * 32;
      size_t ob = (size_t)(rr >> 2) * o_cs + (size_t)(rr & 3) * 2048 + ct * 32;
      float s0 = acc0[j] + rp[(dr + j) * 33 + dc] + b2f(Vbase[vb + dc]);
      float s1 = acc1[j] + rp[(dr + j) * 33 + 16 + dc] + b2f(Vbase[vb + 16 + dc]);
      Obase[ob + dc] = f2b(s0);
      Obase[ob + 16 + dc] = f2b(s1);
    }
  }
}

// pass-2 step on [4 rows x 32 cols]: O = A @ M32lds^T + V, dense row layout [4][2048].
// Waves: colh=wid>>2 (16-col half), ks=wid&3 (K quarter).
__device__ __forceinline__ void step4(const char* smem, float* red,
                                      const u16* __restrict__ A, const u16* __restrict__ V,
                                      u16* __restrict__ O, int ct, int Keff, int rowb,
                                      int wid, int lane) {
  int ks = wid & 3, colh = wid >> 2;
  int fr = lane & 15, fk8 = (lane >> 4) * 8;
  int K4 = Keff >> 2, kw = ks * K4;
  int ar = fr < 4 ? fr : 3;
  const u16* Arow = A + (size_t)ar * 2048 + kw + fk8;
  int off = (colh * 16 + fr) * rowb + (kw + fk8) * 2;
  int sw = (fr & 7) << 4;
  f32x4 acc = {};
  for (int kk = 0; kk < K4; kk += 32)
    acc = mfma16(*(const bf16x8*)(Arow + kk), *(const bf16x8*)(smem + ((off + kk * 2) ^ sw)), acc);
  int dr = (lane >> 4) * 4, dc = lane & 15;
  if (ks != 0) {
    float* rp = red + (colh * 4 + ks) * 272;
#pragma unroll
    for (int j = 0; j < 4; ++j) rp[(dr + j) * 17 + dc] = acc[j];
  }
  __syncthreads();
  if (ks == 0 && dr == 0) {
#pragma unroll
    for (int j = 0; j < 4; ++j) {
      float s = acc[j];
#pragma unroll
      for (int q = 1; q < 4; ++q) s += red[(colh * 4 + q) * 272 + j * 17 + dc];
      int col = ct * 32 + colh * 16 + dc;
      s += b2f(V[(size_t)j * 2048 + col]);
      O[(size_t)j * 2048 + col] = f2b(s);
    }
  }
}

__global__ __launch_bounds__(512) void scan_coop_kernel(
    const u16* __restrict__ M, const u16* __restrict__ M32, const u16* __restrict__ vbuf,
    u16* __restrict__ Sall, u16* __restrict__ ping0, u16* __restrict__ ping1) {
  extern __shared__ char smem[];
  float* red = (float*)(smem + 131072);
  cooperative_groups::grid_group grid = cooperative_groups::this_grid();
  int blk = blockIdx.x;
  int ct = blk >> 1, rg = blk & 1;
  int wid = threadIdx.x >> 6, lane = threadIdx.x & 63;
  int Keff = ((ct >> 4) + 1) << 9;
  int rowb = Keff * 2;

  stage_slice(M, smem, ct, Keff, rowb, wid, lane);
  __syncthreads();

  // pass 1: Shat_j = M Shat_{j-1} + v_j  (Shat_0 = v_0, read from vbuf)
  const u16* A = vbuf;
  int a_cs = 262144;
  for (int j = 1; j <= 31; ++j) {
    u16* O = (j & 1) ? ping0 : ping1;
    step128(smem, red, A, a_cs, vbuf + (size_t)j * 8192, 262144, O, 8192,
            ct, rg, Keff, rowb, wid, lane);
    grid.sync();
    A = O;
    a_cs = 8192;
  }
  // wstack = ping0 (j=31 odd)

  // pass 2: Sall[32(c+1)] = M32 * Sall[32c] + w_c   (rg==0 blocks only)
  if (rg == 0) stage_slice(M32, smem, ct, Keff, rowb, wid, lane);
  __syncthreads();
  for (int c = 0; c < 31; ++c) {
    if (rg == 0)
      step4(smem, red, Sall + (size_t)c * 262144, ping0 + (size_t)c * 8192,
            Sall + (size_t)(c + 1) * 262144, ct, Keff, rowb, wid, lane);
    grid.sync();
  }

  // pass 3: Sall[32c+j+1] = M * Sall[32c+j] + v_{c,j}
  if (rg == 0) stage_slice(M, smem, ct, Keff, rowb, wid, lane);
  __syncthreads();
  for (int j = 0; j < 31; ++j) {
    step128(smem, red, Sall + (size_t)j * 8192, 262144, vbuf + (size_t)j * 8192, 262144,
            Sall + (size_t)(j + 1) * 8192, 262144, ct, rg, Keff, rowb, wid, lane);
    if (j < 30) grid.sync();
  }
}

static inline size_t alignup(size_t x) { return (x + 255) & ~(size_t)255; }

extern "C" void kernel_launch(void* const* d_in, const int* in_sizes, int n_in,
                              void* d_out, int out_size, void* d_ws, size_t ws_size,
                              hipStream_t stream) {
  const int* ids = (const int*)d_in[0];
  const float* embed = (const float*)d_in[1];
  const float* starter = (const float*)d_in[2];
  const float* W = (const float*)d_in[3];
  const float* bvec = (const float*)d_in[4];
  const float* Wout = (const float*)d_in[5];
  const float* bout = (const float*)d_in[6];
  float* out = (float*)d_out;

  char* p = (char*)d_ws;
  auto alloc = [&](size_t bytes) { char* q = p; p += alignup(bytes); return q; };
  u16* Wbf = (u16*)alloc(8388608);
  u16* WbT = (u16*)alloc(8388608);
  u16* Mm = (u16*)alloc(8388608);
  u16* MTm = (u16*)alloc(8388608);
  u16* SQ0 = (u16*)alloc(8388608);
  u16* SQ1 = (u16*)alloc(8388608);
  u16* SQ2 = (u16*)alloc(8388608);
  u16* SQ3 = (u16*)alloc(8388608);
  u16* X2 = (u16*)alloc(524288);  u16* X2T = (u16*)alloc(524288);
  u16* X3 = (u16*)alloc(524288);  u16* X3T = (u16*)alloc(524288);
  u16* P1 = (u16*)alloc(524288);  u16* P1T = (u16*)alloc(524288);
  u16* P2 = (u16*)alloc(524288);  u16* P2T = (u16*)alloc(524288);
  u16* P3 = (u16*)alloc(524288);  u16* P3T = (u16*)alloc(524288);
  u16* Um = (u16*)alloc(2097152);
  u16* Rm = (u16*)alloc(2097152);
  u16* Qm = (u16*)alloc(524288);
  u16* ebf = (u16*)alloc(4194304);
  u16* vbuf = (u16*)alloc(16777216);
  u16* Sall = (u16*)alloc(16777216);
  u16* ping0 = (u16*)alloc(524288);
  u16* ping1 = (u16*)alloc(524288);
  float* yacc = (float*)alloc(8388608);
  u16* ybf = (u16*)alloc(4194304);
  u16* WoutB = (u16*)alloc(32768000);
  float* kvec = (float*)alloc(8192);
  float* h0 = (float*)alloc(2048);
  float* h1 = (float*)alloc(2048);
  if ((size_t)(p - (char*)d_ws) > ws_size) return;

  hipMemsetAsync(h0, 0, 2048, stream);

  cast_w_kernel<<<dim3(16, 16, 4), 256, 0, stream>>>(W, Wbf, WbT);
  cast_f32_bf16_kernel<<<4096, 256, 0, stream>>>(Wout, WoutB, 32000L * 512 / 8);
  gather_e_kernel<<<1024, 256, 0, stream>>>(ids, embed, ebf);
  init_s0_kernel<<<8, 256, 0, stream>>>(starter, Sall);
  assemble_kernel<<<dim3(1024, 6), 256, 0, stream>>>(Wbf, WbT, Mm, MTm, Rm, Um);

  {  // bias chain
    const float* hin = h0;
    float* hout = h1;
    for (int l = 0; l < 4; ++l) {
      bias_step_kernel<<<16, 256, 0, stream>>>(W, bvec, l, hin, hout, kvec);
      float* t = (float*)hin; hin = hout; hout = t;
    }
  }
  const float* cvec = h0;  // h after layer 3

  auto wb = [&](int i) { return Wbf + (size_t)i * 1048576; };
  auto wbt = [&](int i) { return WbT + (size_t)i * 1048576; };
  const size_t Apos = 0, Cpos = (size_t)512 * 1024;
  auto mblk = [&](int i, int j) { return Mm + (size_t)(i * 512) * 2048 + j * 512; };
  auto mtblk = [&](int i, int j) { return MTm + (size_t)(j * 512) * 2048 + i * 512; };

  {  // level A
    G512Args a{};
    int n = 0;
    auto add = [&](const u16* A_, int lda, const u16* B_, int ldb, u16* C_, int ldc, u16* CT_, int ldt) {
      a.g[n++] = G512{A_, B_, C_, CT_, lda, ldb, ldc, ldt};
    };
    add(wb(1) + Apos, 1024, wbt(0) + Apos, 1024, X2, 512, X2T, 512);
    add(wb(1) + Apos, 1024, wbt(0) + Cpos, 1024, P1, 512, P1T, 512);
    add(wb(2) + Apos, 1024, wbt(1) + Cpos, 1024, P3, 512, P3T, 512);
    add(wb(1) + Cpos, 1024, wbt(0) + Cpos, 1024, mblk(1, 0), 2048, mtblk(1, 0), 2048);
    add(wb(2) + Cpos, 1024, wbt(1) + Cpos, 1024, mblk(2, 1), 2048, mtblk(2, 1), 2048);
    add(wb(3) + Apos, 1024, wbt(2) + Cpos, 1024, Rm + 2 * 512, 2048, nullptr, 0);
    add(wb(3) + Cpos, 1024, wbt(2) + Cpos, 1024, mblk(3, 2), 2048, mtblk(3, 2), 2048);
    add(wb(1) + Cpos, 1024, wbt(0) + Apos, 1024, Um + (size_t)1 * 262144, 512, nullptr, 0);
    gemm512_kernel<<<dim3(8, 8, 8), 256, 0, stream>>>(a);
  }
  {  // level B
    G512Args a{};
    int n = 0;
    auto add = [&](const u16* A_, int lda, const u16* B_, int ldb, u16* C_, int ldc, u16* CT_, int ldt) {
      a.g[n++] = G512{A_, B_, C_, CT_, lda, ldb, ldc, ldt};
    };
    add(wb(2) + Apos, 1024, X2T, 512, X3, 512, X3T, 512);
    add(wb(2) + Apos, 1024, P1T, 512, P2, 512, P2T, 512);
    add(wb(2) + Cpos, 1024, P1T, 512, mblk(2, 0), 2048, mtblk(2, 0), 2048);
    add(wb(3) + Apos, 1024, P3T, 512, Rm + 512, 2048, nullptr, 0);
    add(wb(3) + Cpos, 1024, P3T, 512, mblk(3, 1), 2048, mtblk(3, 1), 2048);
    add(wb(2) + Cpos, 1024, X2T, 512, Um + (size_t)2 * 262144, 512, nullptr, 0);
    gemm512_kernel<<<dim3(8, 8, 6), 256, 0, stream>>>(a);
  }
  {  // level C
    G512Args a{};
    int n = 0;
    auto add = [&](const u16* A_, int lda, const u16* B_, int ldb, u16* C_, int ldc, u16* CT_, int ldt) {
      a.g[n++] = G512{A_, B_, C_, CT_, lda, ldb, ldc, ldt};
    };
    add(wb(3) + Apos, 1024, X3T, 512, Qm, 512, nullptr, 0);
    add(wb(3) + Apos, 1024, P2T, 512, Rm, 2048, nullptr, 0);
    add(wb(3) + Cpos, 1024, P2T, 512, mblk(3, 0), 2048, mtblk(3, 0), 2048);
    add(wb(3) + Cpos, 1024, X3T, 512, Um + (size_t)3 * 262144, 512, nullptr, 0);
    gemm512_kernel<<<dim3(8, 8, 4), 256, 0, stream>>>(a);
  }

  // M^32 via 5 triangular squarings
  u16* cur = Mm;
  u16* curT = MTm;
  for (int s = 0; s < 5; ++s) {
    u16* nx = (s & 1) ? SQ2 : SQ0;
    u16* nxT = (s & 1) ? SQ3 : SQ1;
    sq_tri_kernel<<<dim3(4, 4, 10), 256, 0, stream>>>(cur, curT, nx, nxT);
    cur = nx; curT = nxT;
  }
  u16* M32 = cur;  // SQ0

  // v = e @ U^T + k   [4096, 2048] bf16
  gemm128_kernel<true, false, false, true, false><<<dim3(16, 32), 256, 0, stream>>>(
      ebf, 512, Um, 512, 512, (void*)vbuf, 2048, kvec, nullptr, 0);

  // fused 3-pass scan (93 grid syncs), LDS-resident M
  {
    hipFuncSetAttribute((const void*)scan_coop_kernel,
                        hipFuncAttributeMaxDynamicSharedMemorySize, 139776);
    void* args[] = {(void*)&Mm, (void*)&M32, (void*)&vbuf, (void*)&Sall,
                    (void*)&ping0, (void*)&ping1};
    hipLaunchCooperativeKernel((void*)scan_coop_kernel, dim3(128), dim3(512), args, 139776,
                               stream);
  }

  // y = Sall @ R^T + e @ Q^T + c
  gemm128_kernel<false, false, false, false, false><<<dim3(4, 32), 256, 0, stream>>>(
      Sall, 2048, Rm, 2048, 2048, (void*)yacc, 512, nullptr, nullptr, 0);
  gemm128_kernel<true, false, true, true, false><<<dim3(4, 32), 256, 0, stream>>>(
      ebf, 512, Qm, 512, 512, (void*)ybf, 512, cvec, yacc, 512);

  // logits = y @ Wout^T + bout, rows permuted (t*4+b) -> (b*1024+t); XCD-swizzled grid
  gemm128_kernel<false, true, false, true, true><<<dim3(8000), 256, 0, stream>>>(
      ybf, 512, WoutB, 512, 512, (void*)out, 32000, bout, nullptr, 0);
}

// Round 4
// 1910.877 us; speedup vs baseline: 2.1093x; 1.5553x over previous
//
#include <hip/hip_runtime.h>

typedef unsigned short u16;
typedef unsigned int u32;
typedef __attribute__((ext_vector_type(8))) short bf16x8;
typedef __attribute__((ext_vector_type(4))) float f32x4;
typedef __attribute__((ext_vector_type(8))) u16 u16x8;

__device__ __forceinline__ u16 f2b(float f) {
  u32 u = __builtin_bit_cast(u32, f);
  u += 0x7fffu + ((u >> 16) & 1u);
  return (u16)(u >> 16);
}
__device__ __forceinline__ float b2f(u16 h) {
  u32 u = ((u32)h) << 16;
  return __builtin_bit_cast(float, u);
}
__device__ __forceinline__ f32x4 mfma16(bf16x8 a, bf16x8 b, f32x4 c) {
  return __builtin_amdgcn_mfma_f32_16x16x32_bf16(a, b, c, 0, 0, 0);
}
__device__ __host__ __forceinline__ int pidx(int i, int j) { return i * (i + 1) / 2 + j; }

// ---------- cast W f32 [4][1024][1024] -> bf16 copy + per-layer transposed copy
__global__ __launch_bounds__(256) void cast_w_kernel(const float* __restrict__ W,
                                                     u16* __restrict__ Wb,
                                                     u16* __restrict__ WbT) {
  __shared__ u16 tile[64][65];
  int L = blockIdx.z, R0 = blockIdx.y * 64, C0 = blockIdx.x * 64;
  const float* Wl = W + (size_t)L * (1024 * 1024);
  u16* Wbl = Wb + (size_t)L * (1024 * 1024);
  u16* WbTl = WbT + (size_t)L * (1024 * 1024);
  int tr = threadIdx.x >> 6, tc = threadIdx.x & 63;
  for (int i = 0; i < 16; ++i) {
    int r = tr * 16 + i;
    u16 v = f2b(Wl[(size_t)(R0 + r) * 1024 + C0 + tc]);
    Wbl[(size_t)(R0 + r) * 1024 + C0 + tc] = v;
    tile[r][tc] = v;
  }
  __syncthreads();
  for (int i = 0; i < 16; ++i) {
    int r = tr * 16 + i;
    WbTl[(size_t)(C0 + r) * 1024 + R0 + tc] = tile[tc][r];
  }
}

// ---------- generic f32 -> bf16 cast (n multiple of 8)
__global__ __launch_bounds__(256) void cast_f32_bf16_kernel(const float* __restrict__ in,
                                                            u16* __restrict__ out, long n8) {
  long i = (long)blockIdx.x * 256 + threadIdx.x;
  long stride = (long)gridDim.x * 256;
  for (; i < n8; i += stride) {
    const float* s = in + i * 8;
    u16x8 o;
#pragma unroll
    for (int j = 0; j < 8; ++j) o[j] = f2b(s[j]);
    *(u16x8*)(out + i * 8) = o;
  }
}

// ---------- embedding gather -> e_bf [4096(=t*4+b)][512]
__global__ __launch_bounds__(256) void gather_e_kernel(const int* __restrict__ ids,
                                                       const float* __restrict__ embed,
                                                       u16* __restrict__ ebf) {
  int row = blockIdx.x * 4 + (threadIdx.x >> 6);
  int lane = threadIdx.x & 63;
  int t = row >> 2, b = row & 3;
  int id = ids[b * 1024 + t];
  const float* src = embed + (size_t)id * 512 + lane * 8;
  u16x8 o;
#pragma unroll
  for (int j = 0; j < 8; ++j) o[j] = f2b(src[j]);
  *(u16x8*)(ebf + (size_t)row * 512 + lane * 8) = o;
}

// ---------- s0buf [4][2048] = concat(starter) broadcast over batch
__global__ __launch_bounds__(256) void init_s0_kernel(const float* __restrict__ starter,
                                                      u16* __restrict__ s0buf) {
  int i = blockIdx.x * 256 + threadIdx.x;
  if (i < 2048) {
    u16 v = f2b(starter[i]);
    for (int b = 0; b < 4; ++b) s0buf[(size_t)b * 2048 + i] = v;
  }
}

// ---------- diag blocks into packed P0 (val+T), B3 -> R block3, C0 -> U block0
__global__ __launch_bounds__(256) void assemble_kernel(const u16* __restrict__ Wb,
                                                       const u16* __restrict__ WbT,
                                                       u16* __restrict__ Pv0, u16* __restrict__ Pt0,
                                                       u16* __restrict__ Rm, u16* __restrict__ Um) {
  int task = blockIdx.y;
  int e = blockIdx.x * 256 + threadIdx.x;  // 0..262143
  int r = e >> 9, c = e & 511;
  if (task < 4) {
    int i = task;
    size_t boff = (size_t)pidx(i, i) * 262144 + (size_t)r * 512 + c;
    Pv0[boff] = Wb[(size_t)i * 1048576 + (size_t)(512 + r) * 1024 + 512 + c];
    Pt0[boff] = WbT[(size_t)i * 1048576 + (size_t)(512 + r) * 1024 + 512 + c];
  } else if (task == 4) {
    Rm[(size_t)r * 2048 + 3 * 512 + c] = Wb[(size_t)3 * 1048576 + (size_t)r * 1024 + 512 + c];
  } else {
    Um[(size_t)r * 512 + c] = Wb[(size_t)(512 + r) * 1024 + c];
  }
}

// ---------- bias chain: hnew = A_l h + bx_l ; k_l = C_l h + bs_l   (f32, tiny)
__global__ __launch_bounds__(256) void bias_step_kernel(const float* __restrict__ W,
                                                        const float* __restrict__ bv, int layer,
                                                        const float* __restrict__ hin,
                                                        float* __restrict__ hout,
                                                        float* __restrict__ kvec) {
  int wid = threadIdx.x >> 6, lane = threadIdx.x & 63;
  int gw = blockIdx.x * 4 + wid;
  for (int o = gw; o < 1024; o += 64) {
    const float* row = W + (size_t)layer * 1048576 + (size_t)o * 1024;
    float s = 0.f;
    for (int k = lane; k < 512; k += 64) s += row[k] * hin[k];
    for (int off = 32; off; off >>= 1) s += __shfl_down(s, off);
    if (lane == 0) {
      float v = s + bv[layer * 1024 + o];
      if (o < 512) hout[o] = v;
      else kvec[layer * 512 + (o - 512)] = v;
    }
  }
}

// ---------- batched 512x512x512 composer: Out[r,n] = sum_k A[r,k]*B[n,k], optional T copy
struct G512 { const u16* A; const u16* B; u16* C; u16* CT; int lda, ldb, ldc, ldt; };
struct G512Args { G512 g[8]; };

__global__ __launch_bounds__(256) void gemm512_kernel(G512Args args) {
  G512 d = args.g[blockIdx.z];
  int wid = threadIdx.x >> 6, lane = threadIdx.x & 63;
  int wr = wid >> 1, wc = wid & 1;
  int row0 = blockIdx.y * 64 + wr * 32, col0 = blockIdx.x * 64 + wc * 32;
  int fr = lane & 15, fk = (lane >> 4) * 8;
  f32x4 acc[2][2] = {};
  for (int kk = 0; kk < 512; kk += 32) {
    bf16x8 a[2], b[2];
#pragma unroll
    for (int m = 0; m < 2; ++m)
      a[m] = *(const bf16x8*)(d.A + (size_t)(row0 + m * 16 + fr) * d.lda + kk + fk);
#pragma unroll
    for (int n = 0; n < 2; ++n)
      b[n] = *(const bf16x8*)(d.B + (size_t)(col0 + n * 16 + fr) * d.ldb + kk + fk);
#pragma unroll
    for (int m = 0; m < 2; ++m)
#pragma unroll
      for (int n = 0; n < 2; ++n) acc[m][n] = mfma16(a[m], b[n], acc[m][n]);
  }
  int dr = (lane >> 4) * 4, dc = lane & 15;
  for (int m = 0; m < 2; ++m)
    for (int n = 0; n < 2; ++n)
#pragma unroll
      for (int j = 0; j < 4; ++j) {
        int r = row0 + m * 16 + dr + j, c = col0 + n * 16 + dc;
        u16 v = f2b(acc[m][n][j]);
        d.C[(size_t)r * d.ldc + c] = v;
        if (d.CT) d.CT[(size_t)c * d.ldt + r] = v;
      }
}

// ---------- packed triangular squaring: Q = P*P over 10 nonzero 512x512 blocks.
// Packed layout: block (i,j), j<=i, at pidx(i,j)*512*512; val = [r][c], T = [c][r].
__global__ __launch_bounds__(256) void sq_packed_kernel(const u16* __restrict__ Pv,
                                                        const u16* __restrict__ Pt,
                                                        u16* __restrict__ Qv,
                                                        u16* __restrict__ Qt) {
  __shared__ u16 As[128 * 64];
  __shared__ u16 Bs[128 * 64];
  const int ti_[10] = {0, 1, 1, 2, 2, 2, 3, 3, 3, 3};
  const int tj_[10] = {0, 0, 1, 0, 1, 2, 0, 1, 2, 3};
  int t = blockIdx.z;
  int ib = ti_[t], jb = tj_[t];
  int nl = ib - jb + 1;
  int tid = threadIdx.x;
  int wid = tid >> 6, lane = tid & 63;
  int wr = wid >> 1, wc = wid & 1;
  int fr = lane & 15, fkb = (lane >> 4) * 8;
  int rowt = blockIdx.y * 128, colt = blockIdx.x * 128;
  f32x4 acc[4][4] = {};
  for (int lb = 0; lb < nl; ++lb) {
    int l = jb + lb;
    const u16* A = Pv + (size_t)pidx(ib, l) * 262144;  // [r][k]
    const u16* B = Pt + (size_t)pidx(l, jb) * 262144;  // [c][k]
    for (int kk = 0; kk < 512; kk += 64) {
#pragma unroll
      for (int i = 0; i < 4; ++i) {
        int q = i * 256 + tid;
        int r = q >> 3, kc = (q & 7) * 8;
        *(bf16x8*)&As[r * 64 + kc] = *(const bf16x8*)(A + (size_t)(rowt + r) * 512 + kk + kc);
        *(bf16x8*)&Bs[r * 64 + kc] = *(const bf16x8*)(B + (size_t)(colt + r) * 512 + kk + kc);
      }
      __syncthreads();
#pragma unroll
      for (int kh = 0; kh < 64; kh += 32) {
        bf16x8 a[4], b[4];
#pragma unroll
        for (int m = 0; m < 4; ++m)
          a[m] = *(const bf16x8*)&As[(wr * 64 + m * 16 + fr) * 64 + kh + fkb];
#pragma unroll
        for (int n = 0; n < 4; ++n)
          b[n] = *(const bf16x8*)&Bs[(wc * 64 + n * 16 + fr) * 64 + kh + fkb];
#pragma unroll
        for (int m = 0; m < 4; ++m)
#pragma unroll
          for (int n = 0; n < 4; ++n) acc[m][n] = mfma16(a[m], b[n], acc[m][n]);
      }
      __syncthreads();
    }
  }
  size_t obase = (size_t)pidx(ib, jb) * 262144;
  int dr = (lane >> 4) * 4, dc = lane & 15;
  for (int m = 0; m < 4; ++m)
    for (int n = 0; n < 4; ++n)
#pragma unroll
      for (int j = 0; j < 4; ++j) {
        int r = rowt + wr * 64 + m * 16 + dr + j;
        int c = colt + wc * 64 + n * 16 + dc;
        u16 v = f2b(acc[m][n][j]);
        Qv[obase + (size_t)r * 512 + c] = v;
        Qt[obase + (size_t)c * 512 + r] = v;
      }
}

// ---------- tree combine: for node n (0..N-1):
//   dst[n] = P^(2^k) @ src[n] + dst[n],  rows = [4][2048] per node.
// Grid (8 col-tiles of 256, ceil(N/4)); 4 nodes/block -> 16 MFMA rows.
// A (src rows) staged in swizzled LDS; B read from packed power (L2-hot).
__global__ __launch_bounds__(256) void combine_kernel(u16* __restrict__ xdst,
                                                      const u16* __restrict__ xsrc,
                                                      size_t nstride, const u16* __restrict__ Pk,
                                                      int N) {
  extern __shared__ char smem[];
  int tid = threadIdx.x, wid = tid >> 6, lane = tid & 63;
  int ct = blockIdx.x;  // 256-col tile
  int g0 = blockIdx.y * 4;
  int i_blk = ct >> 1;
  int Keff = (i_blk + 1) << 9;
  int rowb = Keff << 1;
  // stage 16 A rows (4 per wave)
  int cpr = Keff >> 3;
  for (int rr = 0; rr < 4; ++rr) {
    int row = wid * 4 + rr;
    int n = g0 + (row >> 2);
    if (n > N - 1) n = N - 1;
    const u16* srow = xsrc + (size_t)n * nstride + (size_t)(row & 3) * 2048;
    int rb = row * rowb, sw = (row & 7) << 4;
    for (int c0 = lane; c0 < cpr; c0 += 64) {
      uint4 v = *(const uint4*)(srow + c0 * 8);
      *(uint4*)(smem + ((rb + c0 * 16) ^ sw)) = v;
    }
  }
  __syncthreads();
  int fr = lane & 15, fk8 = (lane >> 4) * 8;
  int colw = ct * 256 + wid * 64;
  size_t cl[4];
#pragma unroll
  for (int n = 0; n < 4; ++n) cl[n] = (size_t)((colw + n * 16 + fr) & 511) * 512;
  f32x4 acc[4] = {};
  int asw = (fr & 7) << 4;
  for (int jb = 0; jb <= i_blk; ++jb) {
    const u16* Pb = Pk + (size_t)(i_blk * (i_blk + 1) / 2 + jb) * 262144;
    int kg0 = jb << 9;
#pragma unroll 4
    for (int kk = 0; kk < 512; kk += 32) {
      int kf = kk + fk8;
      int aoff = fr * rowb + (kg0 + kf) * 2;
      bf16x8 a = *(const bf16x8*)(smem + (aoff ^ asw));
#pragma unroll
      for (int n = 0; n < 4; ++n) {
        bf16x8 b = *(const bf16x8*)(Pb + cl[n] + kf);
        acc[n] = mfma16(a, b, acc[n]);
      }
    }
  }
  int dr = (lane >> 4) * 4, dc = lane & 15;
#pragma unroll
  for (int n = 0; n < 4; ++n) {
    int col = colw + n * 16 + dc;
#pragma unroll
    for (int j = 0; j < 4; ++j) {
      int fro = dr + j;
      int nd = g0 + (fro >> 2);
      if (nd > N - 1) nd = N - 1;
      u16* drow = xdst + (size_t)nd * nstride + (size_t)(fro & 3) * 2048 + col;
      *drow = f2b(acc[n][j] + b2f(*drow));
    }
  }
}

// ---------- main tiled GEMM: Out[r,n] = sum_k A[r,k]*B[n,k] (+bias[n]) (+prev[r,n])
template <bool OUT_BF16, bool PERM, bool ADD_PREV, bool HAS_BIAS, bool SWZ>
__global__ __launch_bounds__(256) void gemm128_kernel(
    const u16* __restrict__ A, int lda, const u16* __restrict__ B, int ldb, int K,
    void* __restrict__ C, int ldc,
    const float* __restrict__ bias, const float* __restrict__ prev, int ldp) {
  __shared__ u16 As[128 * 64];
  __shared__ u16 Bs[128 * 64];
  int tid = threadIdx.x;
  int wid = tid >> 6, lane = tid & 63;
  int wr = wid >> 1, wc = wid & 1;
  int fr = lane & 15, fkb = (lane >> 4) * 8;
  int rowt, colt;
  if (SWZ) {
    int bid = blockIdx.x;
    int lin = (bid & 7) * 1000 + (bid >> 3);
    rowt = (lin & 31) * 128;
    colt = (lin >> 5) * 128;
  } else {
    rowt = blockIdx.y * 128;
    colt = blockIdx.x * 128;
  }
  f32x4 acc[4][4] = {};
  for (int kk = 0; kk < K; kk += 64) {
#pragma unroll
    for (int i = 0; i < 4; ++i) {
      int q = i * 256 + tid;
      int r = q >> 3, kc = (q & 7) * 8;
      *(bf16x8*)&As[r * 64 + kc] = *(const bf16x8*)(A + (size_t)(rowt + r) * lda + kk + kc);
      *(bf16x8*)&Bs[r * 64 + kc] = *(const bf16x8*)(B + (size_t)(colt + r) * ldb + kk + kc);
    }
    __syncthreads();
#pragma unroll
    for (int kh = 0; kh < 64; kh += 32) {
      bf16x8 a[4], b[4];
#pragma unroll
      for (int m = 0; m < 4; ++m) a[m] = *(const bf16x8*)&As[(wr * 64 + m * 16 + fr) * 64 + kh + fkb];
#pragma unroll
      for (int n = 0; n < 4; ++n) b[n] = *(const bf16x8*)&Bs[(wc * 64 + n * 16 + fr) * 64 + kh + fkb];
#pragma unroll
      for (int m = 0; m < 4; ++m)
#pragma unroll
        for (int n = 0; n < 4; ++n) acc[m][n] = mfma16(a[m], b[n], acc[m][n]);
    }
    __syncthreads();
  }
  int dr = (lane >> 4) * 4, dc = lane & 15;
  for (int m = 0; m < 4; ++m)
    for (int n = 0; n < 4; ++n) {
      int c = colt + wc * 64 + n * 16 + dc;
      float bvv = HAS_BIAS ? bias[c] : 0.f;
#pragma unroll
      for (int j = 0; j < 4; ++j) {
        int r = rowt + wr * 64 + m * 16 + dr + j;
        float v = acc[m][n][j] + bvv;
        if (ADD_PREV) v += prev[(size_t)r * ldp + c];
        int orow = PERM ? ((r & 3) * 1024 + (r >> 2)) : r;
        if (OUT_BF16) ((u16*)C)[(size_t)orow * ldc + c] = f2b(v);
        else ((float*)C)[(size_t)orow * ldc + c] = v;
      }
    }
}

static inline size_t alignup(size_t x) { return (x + 255) & ~(size_t)255; }

extern "C" void kernel_launch(void* const* d_in, const int* in_sizes, int n_in,
                              void* d_out, int out_size, void* d_ws, size_t ws_size,
                              hipStream_t stream) {
  const int* ids = (const int*)d_in[0];
  const float* embed = (const float*)d_in[1];
  const float* starter = (const float*)d_in[2];
  const float* W = (const float*)d_in[3];
  const float* bvec = (const float*)d_in[4];
  const float* Wout = (const float*)d_in[5];
  const float* bout = (const float*)d_in[6];
  float* out = (float*)d_out;

  const size_t SLOT = 2621440;  // elems per packed power (10*512*512)
  char* p = (char*)d_ws;
  auto alloc = [&](size_t bytes) { char* q = p; p += alignup(bytes); return q; };
  u16* Pv = (u16*)alloc(9 * SLOT * 2);   // packed power values, k=0..8
  u16* Pt = (u16*)alloc(9 * SLOT * 2);   // packed power transposes
  u16* Wbf = (u16*)alloc(8388608);
  u16* WbT = (u16*)alloc(8388608);
  u16* X2 = (u16*)alloc(524288);  u16* X2T = (u16*)alloc(524288);
  u16* X3 = (u16*)alloc(524288);  u16* X3T = (u16*)alloc(524288);
  u16* P1 = (u16*)alloc(524288);  u16* P1T = (u16*)alloc(524288);
  u16* P2 = (u16*)alloc(524288);  u16* P2T = (u16*)alloc(524288);
  u16* P3 = (u16*)alloc(524288);  u16* P3T = (u16*)alloc(524288);
  u16* Um = (u16*)alloc(2097152);
  u16* Rm = (u16*)alloc(2097152);
  u16* Qm = (u16*)alloc(524288);
  u16* ebf = (u16*)alloc(4194304);
  u16* s0buf = (u16*)alloc(16384 + 16777216);  // [4][2048] then x[1024][4][2048]
  u16* xbuf = s0buf + 8192;
  float* kvec = (float*)alloc(8192);
  float* h0 = (float*)alloc(2048);
  float* h1 = (float*)alloc(2048);
  if ((size_t)(p - (char*)d_ws) > ws_size) return;
  // aliases onto dead regions:
  u16* WoutB = Pt;             // used only after last squaring (Pt[0..6] dead)
  float* yacc = (float*)Wbf;   // used only after composers (Wbf dead)
  u16* ybf = WbT;              // used only after composers (WbT dead)

  hipMemsetAsync(h0, 0, 2048, stream);

  cast_w_kernel<<<dim3(16, 16, 4), 256, 0, stream>>>(W, Wbf, WbT);
  gather_e_kernel<<<1024, 256, 0, stream>>>(ids, embed, ebf);
  init_s0_kernel<<<8, 256, 0, stream>>>(starter, s0buf);
  assemble_kernel<<<dim3(1024, 6), 256, 0, stream>>>(Wbf, WbT, Pv, Pt, Rm, Um);

  {  // bias chain
    const float* hin = h0;
    float* hout = h1;
    for (int l = 0; l < 4; ++l) {
      bias_step_kernel<<<16, 256, 0, stream>>>(W, bvec, l, hin, hout, kvec);
      float* t = (float*)hin; hin = hout; hout = t;
    }
  }
  const float* cvec = h0;  // h after layer 3

  auto wb = [&](int i) { return Wbf + (size_t)i * 1048576; };
  auto wbt = [&](int i) { return WbT + (size_t)i * 1048576; };
  const size_t Apos = 0, Cpos = (size_t)512 * 1024;
  auto pvblk = [&](int i, int j) { return Pv + (size_t)pidx(i, j) * 262144; };
  auto ptblk = [&](int i, int j) { return Pt + (size_t)pidx(i, j) * 262144; };

  {  // level A
    G512Args a{};
    int n = 0;
    auto add = [&](const u16* A_, int lda, const u16* B_, int ldb, u16* C_, int ldc, u16* CT_, int ldt) {
      a.g[n++] = G512{A_, B_, C_, CT_, lda, ldb, ldc, ldt};
    };
    add(wb(1) + Apos, 1024, wbt(0) + Apos, 1024, X2, 512, X2T, 512);
    add(wb(1) + Apos, 1024, wbt(0) + Cpos, 1024, P1, 512, P1T, 512);
    add(wb(2) + Apos, 1024, wbt(1) + Cpos, 1024, P3, 512, P3T, 512);
    add(wb(1) + Cpos, 1024, wbt(0) + Cpos, 1024, pvblk(1, 0), 512, ptblk(1, 0), 512);
    add(wb(2) + Cpos, 1024, wbt(1) + Cpos, 1024, pvblk(2, 1), 512, ptblk(2, 1), 512);
    add(wb(3) + Apos, 1024, wbt(2) + Cpos, 1024, Rm + 2 * 512, 2048, nullptr, 0);
    add(wb(3) + Cpos, 1024, wbt(2) + Cpos, 1024, pvblk(3, 2), 512, ptblk(3, 2), 512);
    add(wb(1) + Cpos, 1024, wbt(0) + Apos, 1024, Um + (size_t)1 * 262144, 512, nullptr, 0);
    gemm512_kernel<<<dim3(8, 8, 8), 256, 0, stream>>>(a);
  }
  {  // level B
    G512Args a{};
    int n = 0;
    auto add = [&](const u16* A_, int lda, const u16* B_, int ldb, u16* C_, int ldc, u16* CT_, int ldt) {
      a.g[n++] = G512{A_, B_, C_, CT_, lda, ldb, ldc, ldt};
    };
    add(wb(2) + Apos, 1024, X2T, 512, X3, 512, X3T, 512);
    add(wb(2) + Apos, 1024, P1T, 512, P2, 512, P2T, 512);
    add(wb(2) + Cpos, 1024, P1T, 512, pvblk(2, 0), 512, ptblk(2, 0), 512);
    add(wb(3) + Apos, 1024, P3T, 512, Rm + 512, 2048, nullptr, 0);
    add(wb(3) + Cpos, 1024, P3T, 512, pvblk(3, 1), 512, ptblk(3, 1), 512);
    add(wb(2) + Cpos, 1024, X2T, 512, Um + (size_t)2 * 262144, 512, nullptr, 0);
    gemm512_kernel<<<dim3(8, 8, 6), 256, 0, stream>>>(a);
  }
  {  // level C
    G512Args a{};
    int n = 0;
    auto add = [&](const u16* A_, int lda, const u16* B_, int ldb, u16* C_, int ldc, u16* CT_, int ldt) {
      a.g[n++] = G512{A_, B_, C_, CT_, lda, ldb, ldc, ldt};
    };
    add(wb(3) + Apos, 1024, X3T, 512, Qm, 512, nullptr, 0);
    add(wb(3) + Apos, 1024, P2T, 512, Rm, 2048, nullptr, 0);
    add(wb(3) + Cpos, 1024, P2T, 512, pvblk(3, 0), 512, ptblk(3, 0), 512);
    add(wb(3) + Cpos, 1024, X3T, 512, Um + (size_t)3 * 262144, 512, nullptr, 0);
    gemm512_kernel<<<dim3(8, 8, 4), 256, 0, stream>>>(a);
  }

  // powers P_k = M^(2^k), k=1..8 via packed triangular squarings
  for (int s = 0; s < 8; ++s)
    sq_packed_kernel<<<dim3(4, 4, 10), 256, 0, stream>>>(
        Pv + (size_t)s * SLOT, Pt + (size_t)s * SLOT,
        Pv + (size_t)(s + 1) * SLOT, Pt + (size_t)(s + 1) * SLOT);

  // Wout cast (after squarings: aliases dead Pt[0..6])
  cast_f32_bf16_kernel<<<4096, 256, 0, stream>>>(Wout, WoutB, 32000L * 512 / 8);

  // x = v = e @ U^T + k   [4096(=t*4+b)][2048] bf16, in-place scan array
  gemm128_kernel<true, false, false, true, false><<<dim3(16, 32), 256, 0, stream>>>(
      ebf, 512, Um, 512, 512, (void*)xbuf, 2048, kvec, nullptr, 0);

  // Brent-Kung tree scan: x[t] -> S_t (inclusive), uniform operator M.
  {
    hipFuncSetAttribute((const void*)combine_kernel,
                        hipFuncAttributeMaxDynamicSharedMemorySize, 65536);
    // fold s0: x[0] = M s0 + v_0
    combine_kernel<<<dim3(8, 1), 256, 65536, stream>>>(xbuf, s0buf, (size_t)8192, Pv, 1);
    // up-sweep k=0..8 (skip k=9: x[1023] never needed)
    for (int k = 0; k <= 8; ++k) {
      int h = 1 << k, step = 2 << k;
      int p0 = step - 1;
      int N = 1024 >> (k + 1);
      combine_kernel<<<dim3(8, (N + 3) / 4), 256, 65536, stream>>>(
          xbuf + (size_t)p0 * 8192, xbuf + (size_t)(p0 - h) * 8192,
          (size_t)step * 8192, Pv + (size_t)k * SLOT, N);
    }
    // down-sweep d=9..1
    for (int d = 9; d >= 1; --d) {
      int h = 1 << (d - 1), step = 1 << d;
      int p0 = 3 * h - 1;
      int N = (1024 >> d) - 1;
      combine_kernel<<<dim3(8, (N + 3) / 4), 256, 65536, stream>>>(
          xbuf + (size_t)p0 * 8192, xbuf + (size_t)(p0 - h) * 8192,
          (size_t)step * 8192, Pv + (size_t)(d - 1) * SLOT, N);
    }
  }

  // y = S_prev @ R^T + e @ Q^T + c ; S_prev rows = [s0, S_0..S_1022] = s0buf onward
  gemm128_kernel<false, false, false, false, false><<<dim3(4, 32), 256, 0, stream>>>(
      s0buf, 2048, Rm, 2048, 2048, (void*)yacc, 512, nullptr, nullptr, 0);
  gemm128_kernel<true, false, true, true, false><<<dim3(4, 32), 256, 0, stream>>>(
      ebf, 512, Qm, 512, 512, (void*)ybf, 512, cvec, yacc, 512);

  // logits = y @ Wout^T + bout, rows permuted (t*4+b) -> (b*1024+t); XCD-swizzled grid
  gemm128_kernel<false, true, false, true, true><<<dim3(8000), 256, 0, stream>>>(
      ybf, 512, WoutB, 512, 512, (void*)out, 32000, bout, nullptr, 0);
}

// Round 5
// 1822.600 us; speedup vs baseline: 2.2114x; 1.0484x over previous
//
#include <hip/hip_runtime.h>

typedef unsigned short u16;
typedef unsigned int u32;
typedef __attribute__((ext_vector_type(8))) short bf16x8;
typedef __attribute__((ext_vector_type(4))) float f32x4;
typedef __attribute__((ext_vector_type(8))) u16 u16x8;

__device__ __forceinline__ u16 f2b(float f) {
  u32 u = __builtin_bit_cast(u32, f);
  u += 0x7fffu + ((u >> 16) & 1u);
  return (u16)(u >> 16);
}
__device__ __forceinline__ float b2f(u16 h) {
  u32 u = ((u32)h) << 16;
  return __builtin_bit_cast(float, u);
}
__device__ __forceinline__ f32x4 mfma16(bf16x8 a, bf16x8 b, f32x4 c) {
  return __builtin_amdgcn_mfma_f32_16x16x32_bf16(a, b, c, 0, 0, 0);
}
__device__ __host__ __forceinline__ int pidx(int i, int j) { return i * (i + 1) / 2 + j; }

// ---------- cast W f32 [4][1024][1024] -> bf16 copy + per-layer transposed copy
__global__ __launch_bounds__(256) void cast_w_kernel(const float* __restrict__ W,
                                                     u16* __restrict__ Wb,
                                                     u16* __restrict__ WbT) {
  __shared__ u16 tile[64][65];
  int L = blockIdx.z, R0 = blockIdx.y * 64, C0 = blockIdx.x * 64;
  const float* Wl = W + (size_t)L * (1024 * 1024);
  u16* Wbl = Wb + (size_t)L * (1024 * 1024);
  u16* WbTl = WbT + (size_t)L * (1024 * 1024);
  int tr = threadIdx.x >> 6, tc = threadIdx.x & 63;
  for (int i = 0; i < 16; ++i) {
    int r = tr * 16 + i;
    u16 v = f2b(Wl[(size_t)(R0 + r) * 1024 + C0 + tc]);
    Wbl[(size_t)(R0 + r) * 1024 + C0 + tc] = v;
    tile[r][tc] = v;
  }
  __syncthreads();
  for (int i = 0; i < 16; ++i) {
    int r = tr * 16 + i;
    WbTl[(size_t)(C0 + r) * 1024 + R0 + tc] = tile[tc][r];
  }
}

// ---------- generic f32 -> bf16 cast (n multiple of 8)
__global__ __launch_bounds__(256) void cast_f32_bf16_kernel(const float* __restrict__ in,
                                                            u16* __restrict__ out, long n8) {
  long i = (long)blockIdx.x * 256 + threadIdx.x;
  long stride = (long)gridDim.x * 256;
  for (; i < n8; i += stride) {
    const float* s = in + i * 8;
    u16x8 o;
#pragma unroll
    for (int j = 0; j < 8; ++j) o[j] = f2b(s[j]);
    *(u16x8*)(out + i * 8) = o;
  }
}

// ---------- embedding gather -> e_bf [4096(=t*4+b)][512]
__global__ __launch_bounds__(256) void gather_e_kernel(const int* __restrict__ ids,
                                                       const float* __restrict__ embed,
                                                       u16* __restrict__ ebf) {
  int row = blockIdx.x * 4 + (threadIdx.x >> 6);
  int lane = threadIdx.x & 63;
  int t = row >> 2, b = row & 3;
  int id = ids[b * 1024 + t];
  const float* src = embed + (size_t)id * 512 + lane * 8;
  u16x8 o;
#pragma unroll
  for (int j = 0; j < 8; ++j) o[j] = f2b(src[j]);
  *(u16x8*)(ebf + (size_t)row * 512 + lane * 8) = o;
}

// ---------- s0buf [4][2048] = concat(starter) broadcast over batch
__global__ __launch_bounds__(256) void init_s0_kernel(const float* __restrict__ starter,
                                                      u16* __restrict__ s0buf) {
  int i = blockIdx.x * 256 + threadIdx.x;
  if (i < 2048) {
    u16 v = f2b(starter[i]);
    for (int b = 0; b < 4; ++b) s0buf[(size_t)b * 2048 + i] = v;
  }
}

// ---------- diag blocks into packed P0 (val+T), B3 -> R block3, C0 -> U block0
__global__ __launch_bounds__(256) void assemble_kernel(const u16* __restrict__ Wb,
                                                       const u16* __restrict__ WbT,
                                                       u16* __restrict__ Pv0, u16* __restrict__ Pt0,
                                                       u16* __restrict__ Rm, u16* __restrict__ Um) {
  int task = blockIdx.y;
  int e = blockIdx.x * 256 + threadIdx.x;  // 0..262143
  int r = e >> 9, c = e & 511;
  if (task < 4) {
    int i = task;
    size_t boff = (size_t)pidx(i, i) * 262144 + (size_t)r * 512 + c;
    Pv0[boff] = Wb[(size_t)i * 1048576 + (size_t)(512 + r) * 1024 + 512 + c];
    Pt0[boff] = WbT[(size_t)i * 1048576 + (size_t)(512 + r) * 1024 + 512 + c];
  } else if (task == 4) {
    Rm[(size_t)r * 2048 + 3 * 512 + c] = Wb[(size_t)3 * 1048576 + (size_t)r * 1024 + 512 + c];
  } else {
    Um[(size_t)r * 512 + c] = Wb[(size_t)(512 + r) * 1024 + c];
  }
}

// ---------- bias chain: hnew = A_l h + bx_l ; k_l = C_l h + bs_l   (f32, tiny)
__global__ __launch_bounds__(256) void bias_step_kernel(const float* __restrict__ W,
                                                        const float* __restrict__ bv, int layer,
                                                        const float* __restrict__ hin,
                                                        float* __restrict__ hout,
                                                        float* __restrict__ kvec) {
  int wid = threadIdx.x >> 6, lane = threadIdx.x & 63;
  int gw = blockIdx.x * 4 + wid;
  for (int o = gw; o < 1024; o += 64) {
    const float* row = W + (size_t)layer * 1048576 + (size_t)o * 1024;
    float s = 0.f;
    for (int k = lane; k < 512; k += 64) s += row[k] * hin[k];
    for (int off = 32; off; off >>= 1) s += __shfl_down(s, off);
    if (lane == 0) {
      float v = s + bv[layer * 1024 + o];
      if (o < 512) hout[o] = v;
      else kvec[layer * 512 + (o - 512)] = v;
    }
  }
}

// ---------- batched 512x512x512 composer: Out[r,n] = sum_k A[r,k]*B[n,k], optional T copy
struct G512 { const u16* A; const u16* B; u16* C; u16* CT; int lda, ldb, ldc, ldt; };
struct G512Args { G512 g[8]; };

__global__ __launch_bounds__(256) void gemm512_kernel(G512Args args) {
  G512 d = args.g[blockIdx.z];
  int wid = threadIdx.x >> 6, lane = threadIdx.x & 63;
  int wr = wid >> 1, wc = wid & 1;
  int row0 = blockIdx.y * 64 + wr * 32, col0 = blockIdx.x * 64 + wc * 32;
  int fr = lane & 15, fk = (lane >> 4) * 8;
  f32x4 acc[2][2] = {};
  for (int kk = 0; kk < 512; kk += 32) {
    bf16x8 a[2], b[2];
#pragma unroll
    for (int m = 0; m < 2; ++m)
      a[m] = *(const bf16x8*)(d.A + (size_t)(row0 + m * 16 + fr) * d.lda + kk + fk);
#pragma unroll
    for (int n = 0; n < 2; ++n)
      b[n] = *(const bf16x8*)(d.B + (size_t)(col0 + n * 16 + fr) * d.ldb + kk + fk);
#pragma unroll
    for (int m = 0; m < 2; ++m)
#pragma unroll
      for (int n = 0; n < 2; ++n) acc[m][n] = mfma16(a[m], b[n], acc[m][n]);
  }
  int dr = (lane >> 4) * 4, dc = lane & 15;
  for (int m = 0; m < 2; ++m)
    for (int n = 0; n < 2; ++n)
#pragma unroll
      for (int j = 0; j < 4; ++j) {
        int r = row0 + m * 16 + dr + j, c = col0 + n * 16 + dc;
        u16 v = f2b(acc[m][n][j]);
        d.C[(size_t)r * d.ldc + c] = v;
        if (d.CT) d.CT[(size_t)c * d.ldt + r] = v;
      }
}

// ---------- packed triangular squaring: Q = P*P over 10 nonzero 512x512 blocks.
// LDS tiles XOR-swizzled (byte ^= (row&7)<<4) -> conflict-free fragment reads.
__global__ __launch_bounds__(256) void sq_packed_kernel(const u16* __restrict__ Pv,
                                                        const u16* __restrict__ Pt,
                                                        u16* __restrict__ Qv,
                                                        u16* __restrict__ Qt) {
  __shared__ char smem[32768];
  char* As = smem;
  char* Bs = smem + 16384;
  const int ti_[10] = {0, 1, 1, 2, 2, 2, 3, 3, 3, 3};
  const int tj_[10] = {0, 0, 1, 0, 1, 2, 0, 1, 2, 3};
  int t = blockIdx.z;
  int ib = ti_[t], jb = tj_[t];
  int nl = ib - jb + 1;
  int tid = threadIdx.x;
  int wid = tid >> 6, lane = tid & 63;
  int wr = wid >> 1, wc = wid & 1;
  int fr = lane & 15, fkb = (lane >> 4) * 8;
  int rowt = blockIdx.y * 128, colt = blockIdx.x * 128;
  f32x4 acc[4][4] = {};
  for (int lb = 0; lb < nl; ++lb) {
    int l = jb + lb;
    const u16* A = Pv + (size_t)pidx(ib, l) * 262144;  // [r][k]
    const u16* B = Pt + (size_t)pidx(l, jb) * 262144;  // [c][k]
    for (int kk = 0; kk < 512; kk += 64) {
#pragma unroll
      for (int i = 0; i < 4; ++i) {
        int q = i * 256 + tid;
        int r = q >> 3, kc = (q & 7) * 8;
        int so = (r * 128 + kc * 2) ^ ((r & 7) << 4);
        *(bf16x8*)(As + so) = *(const bf16x8*)(A + (size_t)(rowt + r) * 512 + kk + kc);
        *(bf16x8*)(Bs + so) = *(const bf16x8*)(B + (size_t)(colt + r) * 512 + kk + kc);
      }
      __syncthreads();
#pragma unroll
      for (int kh = 0; kh < 64; kh += 32) {
        bf16x8 a[4], b[4];
#pragma unroll
        for (int m = 0; m < 4; ++m) {
          int row = wr * 64 + m * 16 + fr;
          a[m] = *(const bf16x8*)(As + ((row * 128 + (kh + fkb) * 2) ^ ((row & 7) << 4)));
        }
#pragma unroll
        for (int n = 0; n < 4; ++n) {
          int row = wc * 64 + n * 16 + fr;
          b[n] = *(const bf16x8*)(Bs + ((row * 128 + (kh + fkb) * 2) ^ ((row & 7) << 4)));
        }
#pragma unroll
        for (int m = 0; m < 4; ++m)
#pragma unroll
          for (int n = 0; n < 4; ++n) acc[m][n] = mfma16(a[m], b[n], acc[m][n]);
      }
      __syncthreads();
    }
  }
  size_t obase = (size_t)pidx(ib, jb) * 262144;
  int dr = (lane >> 4) * 4, dc = lane & 15;
  for (int m = 0; m < 4; ++m)
    for (int n = 0; n < 4; ++n)
#pragma unroll
      for (int j = 0; j < 4; ++j) {
        int r = rowt + wr * 64 + m * 16 + dr + j;
        int c = colt + wc * 64 + n * 16 + dc;
        u16 v = f2b(acc[m][n][j]);
        Qv[obase + (size_t)r * 512 + c] = v;
        Qt[obase + (size_t)c * 512 + r] = v;
      }
}

// ---------- tree combine: dst[n] = P^(2^k) @ src[n] + dst[n], rows = [4][2048]/node.
__global__ __launch_bounds__(256) void combine_kernel(u16* __restrict__ xdst,
                                                      const u16* __restrict__ xsrc,
                                                      size_t nstride, const u16* __restrict__ Pk,
                                                      int N) {
  extern __shared__ char smem[];
  int tid = threadIdx.x, wid = tid >> 6, lane = tid & 63;
  int ct = blockIdx.x;  // 256-col tile
  int g0 = blockIdx.y * 4;
  int i_blk = ct >> 1;
  int Keff = (i_blk + 1) << 9;
  int rowb = Keff << 1;
  int cpr = Keff >> 3;
  for (int rr = 0; rr < 4; ++rr) {
    int row = wid * 4 + rr;
    int n = g0 + (row >> 2);
    if (n > N - 1) n = N - 1;
    const u16* srow = xsrc + (size_t)n * nstride + (size_t)(row & 3) * 2048;
    int rb = row * rowb, sw = (row & 7) << 4;
    for (int c0 = lane; c0 < cpr; c0 += 64) {
      uint4 v = *(const uint4*)(srow + c0 * 8);
      *(uint4*)(smem + ((rb + c0 * 16) ^ sw)) = v;
    }
  }
  __syncthreads();
  int fr = lane & 15, fk8 = (lane >> 4) * 8;
  int colw = ct * 256 + wid * 64;
  size_t cl[4];
#pragma unroll
  for (int n = 0; n < 4; ++n) cl[n] = (size_t)((colw + n * 16 + fr) & 511) * 512;
  f32x4 acc[4] = {};
  int asw = (fr & 7) << 4;
  for (int jb = 0; jb <= i_blk; ++jb) {
    const u16* Pb = Pk + (size_t)(i_blk * (i_blk + 1) / 2 + jb) * 262144;
    int kg0 = jb << 9;
#pragma unroll 4
    for (int kk = 0; kk < 512; kk += 32) {
      int kf = kk + fk8;
      int aoff = fr * rowb + (kg0 + kf) * 2;
      bf16x8 a = *(const bf16x8*)(smem + (aoff ^ asw));
#pragma unroll
      for (int n = 0; n < 4; ++n) {
        bf16x8 b = *(const bf16x8*)(Pb + cl[n] + kf);
        acc[n] = mfma16(a, b, acc[n]);
      }
    }
  }
  int dr = (lane >> 4) * 4, dc = lane & 15;
#pragma unroll
  for (int n = 0; n < 4; ++n) {
    int col = colw + n * 16 + dc;
#pragma unroll
    for (int j = 0; j < 4; ++j) {
      int fro = dr + j;
      int nd = g0 + (fro >> 2);
      if (nd > N - 1) nd = N - 1;
      u16* drow = xdst + (size_t)nd * nstride + (size_t)(fro & 3) * 2048 + col;
      *drow = f2b(acc[n][j] + b2f(*drow));
    }
  }
}

// ---------- main tiled GEMM: Out[r,n] = sum_k A[r,k]*B[n,k] (+bias[n]) (+prev[r,n])
// LDS XOR-swizzled. PERM+f32 path: LDS-bounce epilogue with full-line float4 stores.
template <bool OUT_BF16, bool PERM, bool ADD_PREV, bool HAS_BIAS, bool SWZ>
__global__ __launch_bounds__(256) void gemm128_kernel(
    const u16* __restrict__ A, int lda, const u16* __restrict__ B, int ldb, int K,
    void* __restrict__ C, int ldc,
    const float* __restrict__ bias, const float* __restrict__ prev, int ldp) {
  __shared__ char smem[32768];
  char* As = smem;
  char* Bs = smem + 16384;
  int tid = threadIdx.x;
  int wid = tid >> 6, lane = tid & 63;
  int wr = wid >> 1, wc = wid & 1;
  int fr = lane & 15, fkb = (lane >> 4) * 8;
  int rowt, colt;
  if (SWZ) {
    int bid = blockIdx.x;
    int lin = (bid & 7) * 1000 + (bid >> 3);
    rowt = (lin & 31) * 128;
    colt = (lin >> 5) * 128;
  } else {
    rowt = blockIdx.y * 128;
    colt = blockIdx.x * 128;
  }
  f32x4 acc[4][4] = {};
  for (int kk = 0; kk < K; kk += 64) {
#pragma unroll
    for (int i = 0; i < 4; ++i) {
      int q = i * 256 + tid;
      int r = q >> 3, kc = (q & 7) * 8;
      int so = (r * 128 + kc * 2) ^ ((r & 7) << 4);
      *(bf16x8*)(As + so) = *(const bf16x8*)(A + (size_t)(rowt + r) * lda + kk + kc);
      *(bf16x8*)(Bs + so) = *(const bf16x8*)(B + (size_t)(colt + r) * ldb + kk + kc);
    }
    __syncthreads();
#pragma unroll
    for (int kh = 0; kh < 64; kh += 32) {
      bf16x8 a[4], b[4];
#pragma unroll
      for (int m = 0; m < 4; ++m) {
        int row = wr * 64 + m * 16 + fr;
        a[m] = *(const bf16x8*)(As + ((row * 128 + (kh + fkb) * 2) ^ ((row & 7) << 4)));
      }
#pragma unroll
      for (int n = 0; n < 4; ++n) {
        int row = wc * 64 + n * 16 + fr;
        b[n] = *(const bf16x8*)(Bs + ((row * 128 + (kh + fkb) * 2) ^ ((row & 7) << 4)));
      }
#pragma unroll
      for (int m = 0; m < 4; ++m)
#pragma unroll
        for (int n = 0; n < 4; ++n) acc[m][n] = mfma16(a[m], b[n], acc[m][n]);
    }
    __syncthreads();
  }
  int dr = (lane >> 4) * 4, dc = lane & 15;
  if (PERM && !OUT_BF16) {
    // LDS-bounce epilogue: 2 phases x 64 rows; stores are 512B-contiguous float4.
    float* sred = (float*)smem;
    for (int ph = 0; ph < 2; ++ph) {
      __syncthreads();
#pragma unroll
      for (int mm = 0; mm < 2; ++mm) {
        int m = ph * 2 + mm;
        int lr = wr * 32 + mm * 16 + dr;
#pragma unroll
        for (int n = 0; n < 4; ++n) {
          int lc = wc * 64 + n * 16 + dc;
#pragma unroll
          for (int j = 0; j < 4; ++j) sred[(lr + j) * 128 + lc] = acc[m][n][j];
        }
      }
      __syncthreads();
#pragma unroll
      for (int it = 0; it < 8; ++it) {
        int lr = it * 8 + (tid >> 5);
        int chunk = tid & 31;
        f32x4 v = *(f32x4*)&sred[lr * 128 + chunk * 4];
        int r = rowt + (lr < 32 ? ph * 32 + lr : 64 + ph * 32 + (lr - 32));
        int orow = (r & 3) * 1024 + (r >> 2);
        int c = colt + chunk * 4;
        if (HAS_BIAS) {
          v[0] += bias[c]; v[1] += bias[c + 1]; v[2] += bias[c + 2]; v[3] += bias[c + 3];
        }
        *(f32x4*)((float*)C + (size_t)orow * ldc + c) = v;
      }
    }
  } else {
    for (int m = 0; m < 4; ++m)
      for (int n = 0; n < 4; ++n) {
        int c = colt + wc * 64 + n * 16 + dc;
        float bvv = HAS_BIAS ? bias[c] : 0.f;
#pragma unroll
        for (int j = 0; j < 4; ++j) {
          int r = rowt + wr * 64 + m * 16 + dr + j;
          float v = acc[m][n][j] + bvv;
          if (ADD_PREV) v += prev[(size_t)r * ldp + c];
          int orow = PERM ? ((r & 3) * 1024 + (r >> 2)) : r;
          if (OUT_BF16) ((u16*)C)[(size_t)orow * ldc + c] = f2b(v);
          else ((float*)C)[(size_t)orow * ldc + c] = v;
        }
      }
  }
}

static inline size_t alignup(size_t x) { return (x + 255) & ~(size_t)255; }

extern "C" void kernel_launch(void* const* d_in, const int* in_sizes, int n_in,
                              void* d_out, int out_size, void* d_ws, size_t ws_size,
                              hipStream_t stream) {
  const int* ids = (const int*)d_in[0];
  const float* embed = (const float*)d_in[1];
  const float* starter = (const float*)d_in[2];
  const float* W = (const float*)d_in[3];
  const float* bvec = (const float*)d_in[4];
  const float* Wout = (const float*)d_in[5];
  const float* bout = (const float*)d_in[6];
  float* out = (float*)d_out;

  const size_t SLOT = 2621440;  // elems per packed power (10*512*512)
  char* p = (char*)d_ws;
  auto alloc = [&](size_t bytes) { char* q = p; p += alignup(bytes); return q; };
  u16* Pv = (u16*)alloc(9 * SLOT * 2);   // packed power values, k=0..8
  u16* Pt = (u16*)alloc(9 * SLOT * 2);   // packed power transposes
  u16* Wbf = (u16*)alloc(8388608);
  u16* WbT = (u16*)alloc(8388608);
  u16* X2 = (u16*)alloc(524288);  u16* X2T = (u16*)alloc(524288);
  u16* X3 = (u16*)alloc(524288);  u16* X3T = (u16*)alloc(524288);
  u16* P1 = (u16*)alloc(524288);  u16* P1T = (u16*)alloc(524288);
  u16* P2 = (u16*)alloc(524288);  u16* P2T = (u16*)alloc(524288);
  u16* P3 = (u16*)alloc(524288);  u16* P3T = (u16*)alloc(524288);
  u16* Um = (u16*)alloc(2097152);
  u16* Rm = (u16*)alloc(2097152);
  u16* Qm = (u16*)alloc(524288);
  u16* ebf = (u16*)alloc(4194304);
  u16* s0buf = (u16*)alloc(16384 + 16777216);  // [4][2048] then x[1024][4][2048]
  u16* xbuf = s0buf + 8192;
  float* kvec = (float*)alloc(8192);
  float* h0 = (float*)alloc(2048);
  float* h1 = (float*)alloc(2048);
  if ((size_t)(p - (char*)d_ws) > ws_size) return;
  // aliases onto dead regions:
  u16* WoutB = Pt;             // used only after last squaring (Pt then dead)
  float* yacc = (float*)Wbf;   // used only after composers (Wbf dead)
  u16* ybf = WbT;              // used only after composers (WbT dead)

  hipMemsetAsync(h0, 0, 2048, stream);

  cast_w_kernel<<<dim3(16, 16, 4), 256, 0, stream>>>(W, Wbf, WbT);
  gather_e_kernel<<<1024, 256, 0, stream>>>(ids, embed, ebf);
  init_s0_kernel<<<8, 256, 0, stream>>>(starter, s0buf);
  assemble_kernel<<<dim3(1024, 6), 256, 0, stream>>>(Wbf, WbT, Pv, Pt, Rm, Um);

  {  // bias chain
    const float* hin = h0;
    float* hout = h1;
    for (int l = 0; l < 4; ++l) {
      bias_step_kernel<<<16, 256, 0, stream>>>(W, bvec, l, hin, hout, kvec);
      float* t = (float*)hin; hin = hout; hout = t;
    }
  }
  const float* cvec = h0;  // h after layer 3

  auto wb = [&](int i) { return Wbf + (size_t)i * 1048576; };
  auto wbt = [&](int i) { return WbT + (size_t)i * 1048576; };
  const size_t Apos = 0, Cpos = (size_t)512 * 1024;
  auto pvblk = [&](int i, int j) { return Pv + (size_t)pidx(i, j) * 262144; };
  auto ptblk = [&](int i, int j) { return Pt + (size_t)pidx(i, j) * 262144; };

  {  // level A
    G512Args a{};
    int n = 0;
    auto add = [&](const u16* A_, int lda, const u16* B_, int ldb, u16* C_, int ldc, u16* CT_, int ldt) {
      a.g[n++] = G512{A_, B_, C_, CT_, lda, ldb, ldc, ldt};
    };
    add(wb(1) + Apos, 1024, wbt(0) + Apos, 1024, X2, 512, X2T, 512);
    add(wb(1) + Apos, 1024, wbt(0) + Cpos, 1024, P1, 512, P1T, 512);
    add(wb(2) + Apos, 1024, wbt(1) + Cpos, 1024, P3, 512, P3T, 512);
    add(wb(1) + Cpos, 1024, wbt(0) + Cpos, 1024, pvblk(1, 0), 512, ptblk(1, 0), 512);
    add(wb(2) + Cpos, 1024, wbt(1) + Cpos, 1024, pvblk(2, 1), 512, ptblk(2, 1), 512);
    add(wb(3) + Apos, 1024, wbt(2) + Cpos, 1024, Rm + 2 * 512, 2048, nullptr, 0);
    add(wb(3) + Cpos, 1024, wbt(2) + Cpos, 1024, pvblk(3, 2), 512, ptblk(3, 2), 512);
    add(wb(1) + Cpos, 1024, wbt(0) + Apos, 1024, Um + (size_t)1 * 262144, 512, nullptr, 0);
    gemm512_kernel<<<dim3(8, 8, 8), 256, 0, stream>>>(a);
  }
  {  // level B
    G512Args a{};
    int n = 0;
    auto add = [&](const u16* A_, int lda, const u16* B_, int ldb, u16* C_, int ldc, u16* CT_, int ldt) {
      a.g[n++] = G512{A_, B_, C_, CT_, lda, ldb, ldc, ldt};
    };
    add(wb(2) + Apos, 1024, X2T, 512, X3, 512, X3T, 512);
    add(wb(2) + Apos, 1024, P1T, 512, P2, 512, P2T, 512);
    add(wb(2) + Cpos, 1024, P1T, 512, pvblk(2, 0), 512, ptblk(2, 0), 512);
    add(wb(3) + Apos, 1024, P3T, 512, Rm + 512, 2048, nullptr, 0);
    add(wb(3) + Cpos, 1024, P3T, 512, pvblk(3, 1), 512, ptblk(3, 1), 512);
    add(wb(2) + Cpos, 1024, X2T, 512, Um + (size_t)2 * 262144, 512, nullptr, 0);
    gemm512_kernel<<<dim3(8, 8, 6), 256, 0, stream>>>(a);
  }
  {  // level C
    G512Args a{};
    int n = 0;
    auto add = [&](const u16* A_, int lda, const u16* B_, int ldb, u16* C_, int ldc, u16* CT_, int ldt) {
      a.g[n++] = G512{A_, B_, C_, CT_, lda, ldb, ldc, ldt};
    };
    add(wb(3) + Apos, 1024, X3T, 512, Qm, 512, nullptr, 0);
    add(wb(3) + Apos, 1024, P2T, 512, Rm, 2048, nullptr, 0);
    add(wb(3) + Cpos, 1024, P2T, 512, pvblk(3, 0), 512, ptblk(3, 0), 512);
    add(wb(3) + Cpos, 1024, X3T, 512, Um + (size_t)3 * 262144, 512, nullptr, 0);
    gemm512_kernel<<<dim3(8, 8, 4), 256, 0, stream>>>(a);
  }

  // powers P_k = M^(2^k), k=1..8 via packed triangular squarings
  for (int s = 0; s < 8; ++s)
    sq_packed_kernel<<<dim3(4, 4, 10), 256, 0, stream>>>(
        Pv + (size_t)s * SLOT, Pt + (size_t)s * SLOT,
        Pv + (size_t)(s + 1) * SLOT, Pt + (size_t)(s + 1) * SLOT);

  // Wout cast (after squarings: aliases dead Pt)
  cast_f32_bf16_kernel<<<4096, 256, 0, stream>>>(Wout, WoutB, 32000L * 512 / 8);

  // x = v = e @ U^T + k   [4096(=t*4+b)][2048] bf16, in-place scan array
  gemm128_kernel<true, false, false, true, false><<<dim3(16, 32), 256, 0, stream>>>(
      ebf, 512, Um, 512, 512, (void*)xbuf, 2048, kvec, nullptr, 0);

  // Brent-Kung tree scan: x[t] -> S_t (inclusive), uniform operator M.
  {
    hipFuncSetAttribute((const void*)combine_kernel,
                        hipFuncAttributeMaxDynamicSharedMemorySize, 65536);
    // fold s0: x[0] = M s0 + v_0
    combine_kernel<<<dim3(8, 1), 256, 65536, stream>>>(xbuf, s0buf, (size_t)8192, Pv, 1);
    // up-sweep k=0..8 (skip k=9: x[1023] never needed)
    for (int k = 0; k <= 8; ++k) {
      int h = 1 << k, step = 2 << k;
      int p0 = step - 1;
      int N = 1024 >> (k + 1);
      combine_kernel<<<dim3(8, (N + 3) / 4), 256, 65536, stream>>>(
          xbuf + (size_t)p0 * 8192, xbuf + (size_t)(p0 - h) * 8192,
          (size_t)step * 8192, Pv + (size_t)k * SLOT, N);
    }
    // down-sweep d=9..1
    for (int d = 9; d >= 1; --d) {
      int h = 1 << (d - 1), step = 1 << d;
      int p0 = 3 * h - 1;
      int N = (1024 >> d) - 1;
      combine_kernel<<<dim3(8, (N + 3) / 4), 256, 65536, stream>>>(
          xbuf + (size_t)p0 * 8192, xbuf + (size_t)(p0 - h) * 8192,
          (size_t)step * 8192, Pv + (size_t)(d - 1) * SLOT, N);
    }
  }

  // y = S_prev @ R^T + e @ Q^T + c ; S_prev rows = [s0, S_0..S_1022] = s0buf onward
  gemm128_kernel<false, false, false, false, false><<<dim3(4, 32), 256, 0, stream>>>(
      s0buf, 2048, Rm, 2048, 2048, (void*)yacc, 512, nullptr, nullptr, 0);
  gemm128_kernel<true, false, true, true, false><<<dim3(4, 32), 256, 0, stream>>>(
      ebf, 512, Qm, 512, 512, (void*)ybf, 512, cvec, yacc, 512);

  // logits = y @ Wout^T + bout, rows permuted (t*4+b) -> (b*1024+t); XCD-swizzled grid
  gemm128_kernel<false, true, false, true, true><<<dim3(8000), 256, 0, stream>>>(
      ybf, 512, WoutB, 512, 512, (void*)out, 32000, bout, nullptr, 0);
}